// Round 1
// baseline (313.168 us; speedup 1.0000x reference)
//
#include <hip/hip_runtime.h>
#include <cstdint>
#include <cstddef>

typedef unsigned short u16;
typedef short bf16x8 __attribute__((ext_vector_type(8)));
typedef float f32x4 __attribute__((ext_vector_type(4)));

constexpr int Ns = 512;   // N
constexpr int Dd = 128;   // D
constexpr int Cc = 128;   // C
#define EPSV 1e-5f

__device__ __forceinline__ u16 f2bf(float f){
    uint32_t u = __float_as_uint(f);
    uint32_t r = (u + 0x7fffu + ((u >> 16) & 1u)) >> 16;
    return (u16)r;
}
__device__ __forceinline__ float bf2f(u16 h){
    return __uint_as_float(((uint32_t)h) << 16);
}
__device__ __forceinline__ float sigmoidf_(float x){
    return 1.0f / (1.0f + __expf(-x));
}

// ---------------------------------------------------------------------------
// K0: weights -> bf16, transposed [n][k].  Order: Wl,Wlg,Wr,Wrg,Wog,Wo
// ---------------------------------------------------------------------------
__global__ void k_prep(const float* __restrict__ Wl, const float* __restrict__ Wlg,
                       const float* __restrict__ Wr, const float* __restrict__ Wrg,
                       const float* __restrict__ Wog, const float* __restrict__ Wo,
                       u16* __restrict__ Wt){
    int idx = blockIdx.x * 256 + threadIdx.x;
    if (idx >= 6 * 16384) return;
    int m = idx >> 14; int nk = idx & 16383; int n = nk >> 7; int k = nk & 127;
    const float* W = (m == 0) ? Wl : (m == 1) ? Wlg : (m == 2) ? Wr
                   : (m == 3) ? Wrg : (m == 4) ? Wog : Wo;
    Wt[idx] = f2bf(W[k * Cc + n]);
}

// ---------------------------------------------------------------------------
// K1: LN(x) then 5 GEMMs (Wl,Wlg -> left; Wr,Wrg -> right; Wog -> og)
// Block: 64 rows = 8 a-values x 8 b-values.  256 threads / 4 waves.
// left/right stored k-blocked: [c][k/8][i][k%8]  (bf16)
// og stored natural [a][b][c] (bf16, post-sigmoid)
// ---------------------------------------------------------------------------
__global__ __launch_bounds__(256) void k1(
    const float* __restrict__ x, const float* __restrict__ g_ln, const float* __restrict__ b_ln,
    const u16* __restrict__ Wt,
    const float* __restrict__ bl, const float* __restrict__ blg,
    const float* __restrict__ br, const float* __restrict__ brg,
    const float* __restrict__ bog,
    u16* __restrict__ left, u16* __restrict__ right, u16* __restrict__ og)
{
    __shared__ u16  lA[64][136];       // bf16 xn tile, padded (+8) for bank spread
    __shared__ float redS[64][4];
    __shared__ float redQ[64][4];
    __shared__ float stats[64][2];
    __shared__ float gln[128], bln[128];
    __shared__ u16  lS[4][32][72];     // per-wave store staging [c_local][row], stride 72 (16B align + banks)

    const int t   = threadIdx.x;
    const int bid = blockIdx.x;
    const int a0  = (bid >> 6) << 3;
    const int b0  = (bid & 63) << 3;
    if (t < 128){ gln[t] = g_ln[t]; bln[t] = b_ln[t]; }

    const int r = t >> 2, q = t & 3;
    const int aa = a0 + (r & 7), bb = b0 + (r >> 3);
    const float4* xrow = reinterpret_cast<const float4*>(x + ((size_t)aa * Ns + bb) * Dd);
    float4 xv[8];
    float s1 = 0.f, s2 = 0.f;
#pragma unroll
    for (int i2 = 0; i2 < 8; ++i2){
        float4 v = xrow[q + 4 * i2];
        xv[i2] = v;
        s1 += v.x + v.y + v.z + v.w;
        s2 += v.x * v.x + v.y * v.y + v.z * v.z + v.w * v.w;
    }
    redS[r][q] = s1; redQ[r][q] = s2;
    __syncthreads();
    if (t < 64){
        float ss = redS[t][0] + redS[t][1] + redS[t][2] + redS[t][3];
        float qq = redQ[t][0] + redQ[t][1] + redQ[t][2] + redQ[t][3];
        float mm = ss * (1.0f / 128.0f);
        float var = qq * (1.0f / 128.0f) - mm * mm;
        stats[t][0] = mm;
        stats[t][1] = rsqrtf(var + EPSV);
    }
    __syncthreads();
    {
        const float mm = stats[r][0], rsv = stats[r][1];
#pragma unroll
        for (int i2 = 0; i2 < 8; ++i2){
            const int d = (q + 4 * i2) * 4;
            ushort4 o;
            o.x = f2bf((xv[i2].x - mm) * rsv * gln[d + 0] + bln[d + 0]);
            o.y = f2bf((xv[i2].y - mm) * rsv * gln[d + 1] + bln[d + 1]);
            o.z = f2bf((xv[i2].z - mm) * rsv * gln[d + 2] + bln[d + 2]);
            o.w = f2bf((xv[i2].w - mm) * rsv * gln[d + 3] + bln[d + 3]);
            *reinterpret_cast<ushort4*>(&lA[r][d]) = o;
        }
    }
    __syncthreads();

    const int w = t >> 6, l = t & 63;
    const int lrow = l & 15, lk = (l >> 4) << 3;
    const int nb = w * 32;
    const int orow = (l >> 4) << 2;
    const size_t kb = (size_t)(a0 >> 3);
    const f32x4 zero4 = {0.f, 0.f, 0.f, 0.f};

#pragma unroll 1
    for (int pair = 0; pair < 2; ++pair){
        const u16* WV = Wt + (size_t)(pair * 2 + 0) * 16384;
        const u16* WG = Wt + (size_t)(pair * 2 + 1) * 16384;
        const float* bV = pair ? br : bl;
        const float* bG = pair ? brg : blg;
        u16* dst = pair ? right : left;
        f32x4 accV[4][2], accG[4][2];
#pragma unroll
        for (int rf = 0; rf < 4; ++rf)
#pragma unroll
            for (int cf = 0; cf < 2; ++cf){ accV[rf][cf] = zero4; accG[rf][cf] = zero4; }
#pragma unroll
        for (int ks = 0; ks < 4; ++ks){
            const int k0 = ks * 32 + lk;
            bf16x8 af[4];
#pragma unroll
            for (int rf = 0; rf < 4; ++rf)
                af[rf] = *reinterpret_cast<const bf16x8*>(&lA[rf * 16 + lrow][k0]);
#pragma unroll
            for (int cf = 0; cf < 2; ++cf){
                const int col = nb + cf * 16 + lrow;
                bf16x8 bv = *reinterpret_cast<const bf16x8*>(WV + (size_t)col * 128 + k0);
                bf16x8 bg = *reinterpret_cast<const bf16x8*>(WG + (size_t)col * 128 + k0);
#pragma unroll
                for (int rf = 0; rf < 4; ++rf){
                    accV[rf][cf] = __builtin_amdgcn_mfma_f32_16x16x32_bf16(af[rf], bv, accV[rf][cf], 0, 0, 0);
                    accG[rf][cf] = __builtin_amdgcn_mfma_f32_16x16x32_bf16(af[rf], bg, accG[rf][cf], 0, 0, 0);
                }
            }
        }
        // gate + stage transpose [c][row] in per-wave LDS
#pragma unroll
        for (int cf = 0; cf < 2; ++cf){
            const int col = nb + cf * 16 + lrow;
            const float bVv = bV[col], bGv = bG[col];
#pragma unroll
            for (int rf = 0; rf < 4; ++rf){
#pragma unroll
                for (int j = 0; j < 4; ++j){
                    const float vv = accV[rf][cf][j] + bVv;
                    const float gg = accG[rf][cf][j] + bGv;
                    const int row = rf * 16 + orow + j;
                    lS[w][cf * 16 + lrow][row] = f2bf(sigmoidf_(gg) * vv);
                }
            }
        }
        __syncthreads();
        // store: per c, 64 contiguous elements (=128 B) in k-blocked layout
#pragma unroll
        for (int it = 0; it < 4; ++it){
            const int cl = it * 8 + (l >> 3);
            const int chunk = l & 7;
            const int cg = nb + cl;
            int4 vdat = *reinterpret_cast<const int4*>(&lS[w][cl][chunk * 8]);
            size_t base = (((size_t)cg * 64 + kb) * Ns + b0) * 8 + (size_t)chunk * 8;
            *reinterpret_cast<int4*>(dst + base) = vdat;
        }
        __syncthreads();
    }

    // og group (Wog), direct global stores, post-sigmoid
    {
        const u16* WO = Wt + (size_t)4 * 16384;
        f32x4 acc[4][2];
#pragma unroll
        for (int rf = 0; rf < 4; ++rf)
#pragma unroll
            for (int cf = 0; cf < 2; ++cf) acc[rf][cf] = zero4;
#pragma unroll
        for (int ks = 0; ks < 4; ++ks){
            const int k0 = ks * 32 + lk;
            bf16x8 af[4];
#pragma unroll
            for (int rf = 0; rf < 4; ++rf)
                af[rf] = *reinterpret_cast<const bf16x8*>(&lA[rf * 16 + lrow][k0]);
#pragma unroll
            for (int cf = 0; cf < 2; ++cf){
                bf16x8 bv = *reinterpret_cast<const bf16x8*>(WO + (size_t)(nb + cf * 16 + lrow) * 128 + k0);
#pragma unroll
                for (int rf = 0; rf < 4; ++rf)
                    acc[rf][cf] = __builtin_amdgcn_mfma_f32_16x16x32_bf16(af[rf], bv, acc[rf][cf], 0, 0, 0);
            }
        }
#pragma unroll
        for (int cf = 0; cf < 2; ++cf){
            const int col = nb + cf * 16 + lrow;
            const float bOv = bog[col];
#pragma unroll
            for (int rf = 0; rf < 4; ++rf){
#pragma unroll
                for (int j = 0; j < 4; ++j){
                    const int row = rf * 16 + orow + j;
                    const float val = sigmoidf_(acc[rf][cf][j] + bOv);
                    og[((size_t)(a0 + (row & 7)) * Ns + (b0 + (row >> 3))) * Cc + col] = f2bf(val);
                }
            }
        }
    }
}

// ---------------------------------------------------------------------------
// K2: out_mid[c][i][j] = sum_k left[c][k][i] * right[c][k][j]   (per-channel GEMM)
// Block 256 thr / 4 waves, 128x128 tile, wave = 64x64.  Direct global fragment
// loads (k-blocked layout makes each lane's 8 k's 16 B contiguous).
// ---------------------------------------------------------------------------
__global__ __launch_bounds__(256) void k2(const u16* __restrict__ left,
                                          const u16* __restrict__ right,
                                          u16* __restrict__ om)
{
    const int c = blockIdx.z;
    const int t = threadIdx.x, w = t >> 6, l = t & 63;
    const int wr = w >> 1, wc = w & 1;
    const int ib = blockIdx.y * 128 + wr * 64;
    const int jb = blockIdx.x * 128 + wc * 64;
    const int lrow = l & 15, lkb = l >> 4;
    const u16* Lc = left  + (size_t)c * (64 * Ns * 8);
    const u16* Rc = right + (size_t)c * (64 * Ns * 8);
    const f32x4 zero4 = {0.f, 0.f, 0.f, 0.f};
    f32x4 acc[4][4];
#pragma unroll
    for (int rf = 0; rf < 4; ++rf)
#pragma unroll
        for (int cf = 0; cf < 4; ++cf) acc[rf][cf] = zero4;

#pragma unroll 4
    for (int ks = 0; ks < 16; ++ks){
        const size_t kbrow = (size_t)(ks * 4 + lkb) * Ns;
        bf16x8 af[4], bfr[4];
#pragma unroll
        for (int rf = 0; rf < 4; ++rf)
            af[rf] = *reinterpret_cast<const bf16x8*>(Lc + (kbrow + ib + rf * 16 + lrow) * 8);
#pragma unroll
        for (int cf = 0; cf < 4; ++cf)
            bfr[cf] = *reinterpret_cast<const bf16x8*>(Rc + (kbrow + jb + cf * 16 + lrow) * 8);
#pragma unroll
        for (int rf = 0; rf < 4; ++rf)
#pragma unroll
            for (int cf = 0; cf < 4; ++cf)
                acc[rf][cf] = __builtin_amdgcn_mfma_f32_16x16x32_bf16(af[rf], bfr[cf], acc[rf][cf], 0, 0, 0);
    }
    const int orow = (l >> 4) << 2;
    u16* obase = om + (size_t)c * Ns * Ns;
#pragma unroll
    for (int rf = 0; rf < 4; ++rf)
#pragma unroll
        for (int j2 = 0; j2 < 4; ++j2){
            const int i = ib + rf * 16 + orow + j2;
            u16* orow_p = obase + (size_t)i * Ns + jb;
#pragma unroll
            for (int cf = 0; cf < 4; ++cf)
                orow_p[cf * 16 + lrow] = f2bf(acc[rf][cf][j2]);
        }
}

// ---------------------------------------------------------------------------
// K3: final = sigmoid(og) * (LN_c(out_mid) @ Wo + bo), fp32 out [i][j][c]
// Block: one i, 64 j.  256 thr / 4 waves.
// ---------------------------------------------------------------------------
__global__ __launch_bounds__(256) void k3(
    const u16* __restrict__ om, const u16* __restrict__ og, const u16* __restrict__ Wt,
    const float* __restrict__ g2, const float* __restrict__ b2, const float* __restrict__ bo,
    float* __restrict__ out)
{
    __shared__ u16  X[64][136];   // xn2 [j][c] bf16
    __shared__ u16  O[64][136];   // og tile [j][c] bf16
    __shared__ float redS[64][4];
    __shared__ float redQ[64][4];
    __shared__ float stats[64][2];
    __shared__ float sg2[128], sb2[128];
    const int i  = blockIdx.y;
    const int j0 = blockIdx.x * 64;
    const int t  = threadIdx.x;
    if (t < 128){ sg2[t] = g2[t]; sb2[t] = b2[t]; }
    {   // load out_mid (transpose [c][j] -> [j][c])
        const int c = t >> 1, jh = (t & 1) * 32;
        const u16* src = om + (size_t)c * Ns * Ns + (size_t)i * Ns + j0 + jh;
#pragma unroll
        for (int s = 0; s < 8; ++s){
            ushort4 v = reinterpret_cast<const ushort4*>(src)[s];
            const int jj = jh + s * 4;
            X[jj + 0][c] = v.x; X[jj + 1][c] = v.y; X[jj + 2][c] = v.z; X[jj + 3][c] = v.w;
        }
    }
    {   // load og tile (natural)
        const int jj = t >> 2, qq = t & 3;
        const u16* src = og + ((size_t)i * Ns + j0 + jj) * Cc + qq * 32;
#pragma unroll
        for (int s = 0; s < 4; ++s)
            *reinterpret_cast<int4*>(&O[jj][qq * 32 + s * 8]) = reinterpret_cast<const int4*>(src)[s];
    }
    __syncthreads();
    const int r = t >> 2, q = t & 3;
    {
        float s1 = 0.f, s2v = 0.f;
#pragma unroll
        for (int e = 0; e < 32; ++e){
            const float v = bf2f(X[r][q * 32 + e]);
            s1 += v; s2v += v * v;
        }
        redS[r][q] = s1; redQ[r][q] = s2v;
    }
    __syncthreads();
    if (t < 64){
        float ss = redS[t][0] + redS[t][1] + redS[t][2] + redS[t][3];
        float qq2 = redQ[t][0] + redQ[t][1] + redQ[t][2] + redQ[t][3];
        float mm = ss * (1.0f / 128.0f);
        float var = qq2 * (1.0f / 128.0f) - mm * mm;
        stats[t][0] = mm; stats[t][1] = rsqrtf(var + EPSV);
    }
    __syncthreads();
    {
        const float mm = stats[r][0], rsv = stats[r][1];
#pragma unroll
        for (int e = 0; e < 32; ++e){
            const int cc = q * 32 + e;
            const float v = bf2f(X[r][cc]);
            X[r][cc] = f2bf((v - mm) * rsv * sg2[cc] + sb2[cc]);
        }
    }
    __syncthreads();
    const int w = t >> 6, l = t & 63;
    const int lrow = l & 15, lk = (l >> 4) << 3, nbv = w * 32, orow = (l >> 4) << 2;
    const u16* WO = Wt + (size_t)5 * 16384;
    const f32x4 zero4 = {0.f, 0.f, 0.f, 0.f};
    f32x4 acc[4][2];
#pragma unroll
    for (int rf = 0; rf < 4; ++rf)
#pragma unroll
        for (int cf = 0; cf < 2; ++cf) acc[rf][cf] = zero4;
#pragma unroll
    for (int ks = 0; ks < 4; ++ks){
        const int k0 = ks * 32 + lk;
        bf16x8 af[4];
#pragma unroll
        for (int rf = 0; rf < 4; ++rf)
            af[rf] = *reinterpret_cast<const bf16x8*>(&X[rf * 16 + lrow][k0]);
#pragma unroll
        for (int cf = 0; cf < 2; ++cf){
            bf16x8 bv = *reinterpret_cast<const bf16x8*>(WO + (size_t)(nbv + cf * 16 + lrow) * 128 + k0);
#pragma unroll
            for (int rf = 0; rf < 4; ++rf)
                acc[rf][cf] = __builtin_amdgcn_mfma_f32_16x16x32_bf16(af[rf], bv, acc[rf][cf], 0, 0, 0);
        }
    }
#pragma unroll
    for (int cf = 0; cf < 2; ++cf){
        const int cg = nbv + cf * 16 + lrow;
        const float bov = bo[cg];
#pragma unroll
        for (int rf = 0; rf < 4; ++rf){
#pragma unroll
            for (int j = 0; j < 4; ++j){
                const int row = rf * 16 + orow + j;
                const float gate = bf2f(O[row][cg]);   // sigmoid already applied in k1
                out[((size_t)i * Ns + j0 + row) * Cc + cg] = gate * (acc[rf][cf][j] + bov);
            }
        }
    }
}

// ---------------------------------------------------------------------------
extern "C" void kernel_launch(void* const* d_in, const int* in_sizes, int n_in,
                              void* d_out, int out_size, void* d_ws, size_t ws_size,
                              hipStream_t stream)
{
    const float* x    = (const float*)d_in[0];
    const float* ling = (const float*)d_in[1];
    const float* linb = (const float*)d_in[2];
    const float* loutg= (const float*)d_in[3];
    const float* loutb= (const float*)d_in[4];
    const float* Wl   = (const float*)d_in[5];
    const float* bl   = (const float*)d_in[6];
    const float* Wr   = (const float*)d_in[7];
    const float* br   = (const float*)d_in[8];
    const float* Wo   = (const float*)d_in[9];
    const float* bo   = (const float*)d_in[10];
    const float* Wlg  = (const float*)d_in[11];
    const float* blg  = (const float*)d_in[12];
    const float* Wrg  = (const float*)d_in[13];
    const float* brg  = (const float*)d_in[14];
    const float* Wog  = (const float*)d_in[15];
    const float* bog  = (const float*)d_in[16];

    char* ws = (char*)d_ws;
    u16* Wt = (u16*)ws;
    const size_t off = 256 * 1024;
    const size_t SZ  = (size_t)33554432 * 2;   // 64 MiB per bf16 tensor
    u16* left  = (u16*)(ws + off);
    u16* right = (u16*)(ws + off + SZ);
    u16* og    = (u16*)(ws + off + 2 * SZ);
    u16* om    = (u16*)(ws + off + 3 * SZ);

    hipLaunchKernelGGL(k_prep, dim3(384), dim3(256), 0, stream, Wl, Wlg, Wr, Wrg, Wog, Wo, Wt);
    hipLaunchKernelGGL(k1, dim3(4096), dim3(256), 0, stream,
                       x, ling, linb, Wt, bl, blg, br, brg, bog, left, right, og);
    hipLaunchKernelGGL(k2, dim3(4, 4, 128), dim3(256), 0, stream, left, right, om);
    hipLaunchKernelGGL(k3, dim3(8, 512), dim3(256), 0, stream, om, og, Wt, loutg, loutb, bo, (float*)d_out);
}

// Round 2
// 277.456 us; speedup vs baseline: 1.1287x; 1.1287x over previous
//
#include <hip/hip_runtime.h>
#include <hip/hip_bf16.h>
#include <cstdint>
#include <cstddef>

typedef unsigned short u16;
typedef short bf16x8 __attribute__((ext_vector_type(8)));
typedef float f32x4 __attribute__((ext_vector_type(4)));

constexpr int Ns = 512;   // N
constexpr int Dd = 128;   // D
constexpr int Cc = 128;   // C
#define EPSV 1e-5f

__device__ __forceinline__ u16 f2bf(float f){
    // native conversion: backend fuses adjacent pairs into v_cvt_pk_bf16_f32
    __hip_bfloat16 h = __float2bfloat16(f);
    return *reinterpret_cast<u16*>(&h);
}
__device__ __forceinline__ float bf2f(u16 h){
    return __uint_as_float(((uint32_t)h) << 16);
}
__device__ __forceinline__ float sigmoidf_(float x){
    return 1.0f / (1.0f + __expf(-x));
}

// ---------------------------------------------------------------------------
// K0: weights -> bf16, transposed [n][k].  Order: Wl,Wlg,Wr,Wrg,Wog,Wo
// ---------------------------------------------------------------------------
__global__ void k_prep(const float* __restrict__ Wl, const float* __restrict__ Wlg,
                       const float* __restrict__ Wr, const float* __restrict__ Wrg,
                       const float* __restrict__ Wog, const float* __restrict__ Wo,
                       u16* __restrict__ Wt){
    int idx = blockIdx.x * 256 + threadIdx.x;
    if (idx >= 6 * 16384) return;
    int m = idx >> 14; int nk = idx & 16383; int n = nk >> 7; int k = nk & 127;
    const float* W = (m == 0) ? Wl : (m == 1) ? Wlg : (m == 2) ? Wr
                   : (m == 3) ? Wrg : (m == 4) ? Wog : Wo;
    Wt[idx] = f2bf(W[k * Cc + n]);
}

// ---------------------------------------------------------------------------
// K1: LN(x) then 5 GEMMs (Wl,Wlg -> left; Wr,Wrg -> right; Wog -> og)
// Block: 64 rows = 8 a-values x 8 b-values.  256 threads / 4 waves.
// left/right k-blocked: [c][k/8][j][k%8] (bf16).  og natural [i][j][c] (bf16).
// LN stats via 4-lane shuffle (no LDS, no barrier).  lS staging is wave-local.
// ---------------------------------------------------------------------------
__global__ __launch_bounds__(256) void k1(
    const float* __restrict__ x, const float* __restrict__ g_ln, const float* __restrict__ b_ln,
    const u16* __restrict__ Wt,
    const float* __restrict__ bl, const float* __restrict__ blg,
    const float* __restrict__ br, const float* __restrict__ brg,
    const float* __restrict__ bog,
    u16* __restrict__ left, u16* __restrict__ right, u16* __restrict__ og)
{
    __shared__ u16  lA[64][136];       // bf16 xn tile (padded)
    __shared__ u16  lSbuf[9216];       // aliased: pair staging [4][32][72]  /  og staging [64][132]
    __shared__ float gln[128], bln[128];

    const int t   = threadIdx.x;
    const int bid = blockIdx.x;
    const int a0  = (bid >> 6) << 3;
    const int b0  = (bid & 63) << 3;
    if (t < 128){ gln[t] = g_ln[t]; bln[t] = b_ln[t]; }

    const int r = t >> 2, q = t & 3;
    const int aa = a0 + (r & 7), bb = b0 + (r >> 3);
    const float4* xrow = reinterpret_cast<const float4*>(x + ((size_t)aa * Ns + bb) * Dd);
    float4 xv[8];
    float s1 = 0.f, s2 = 0.f;
#pragma unroll
    for (int i2 = 0; i2 < 8; ++i2){
        float4 v = xrow[q + 4 * i2];
        xv[i2] = v;
        s1 += v.x + v.y + v.z + v.w;
        s2 += v.x * v.x + v.y * v.y + v.z * v.z + v.w * v.w;
    }
    // 4-lane reduce (threads of one row are consecutive lanes)
    s1 += __shfl_xor(s1, 1); s1 += __shfl_xor(s1, 2);
    s2 += __shfl_xor(s2, 1); s2 += __shfl_xor(s2, 2);
    const float mm  = s1 * (1.0f / 128.0f);
    const float rsv = rsqrtf(s2 * (1.0f / 128.0f) - mm * mm + EPSV);
    __syncthreads();                  // gln/bln ready
    {
#pragma unroll
        for (int i2 = 0; i2 < 8; ++i2){
            const int d = (q + 4 * i2) * 4;
            ushort4 o;
            o.x = f2bf((xv[i2].x - mm) * rsv * gln[d + 0] + bln[d + 0]);
            o.y = f2bf((xv[i2].y - mm) * rsv * gln[d + 1] + bln[d + 1]);
            o.z = f2bf((xv[i2].z - mm) * rsv * gln[d + 2] + bln[d + 2]);
            o.w = f2bf((xv[i2].w - mm) * rsv * gln[d + 3] + bln[d + 3]);
            *reinterpret_cast<ushort4*>(&lA[r][d]) = o;
        }
    }
    __syncthreads();                  // lA ready for all waves

    const int w = t >> 6, l = t & 63;
    const int lrow = l & 15, lk = (l >> 4) << 3;
    const int nb = w * 32;
    const int orow = (l >> 4) << 2;
    const size_t kb = (size_t)(a0 >> 3);
    const f32x4 zero4 = {0.f, 0.f, 0.f, 0.f};

#pragma unroll 1
    for (int pair = 0; pair < 2; ++pair){
        const u16* WV = Wt + (size_t)(pair * 2 + 0) * 16384;
        const u16* WG = Wt + (size_t)(pair * 2 + 1) * 16384;
        const float* bV = pair ? br : bl;
        const float* bG = pair ? brg : blg;
        u16* dst = pair ? right : left;
        f32x4 accV[4][2], accG[4][2];
#pragma unroll
        for (int rf = 0; rf < 4; ++rf)
#pragma unroll
            for (int cf = 0; cf < 2; ++cf){ accV[rf][cf] = zero4; accG[rf][cf] = zero4; }
#pragma unroll
        for (int ks = 0; ks < 4; ++ks){
            const int k0 = ks * 32 + lk;
            bf16x8 af[4];
#pragma unroll
            for (int rf = 0; rf < 4; ++rf)
                af[rf] = *reinterpret_cast<const bf16x8*>(&lA[rf * 16 + lrow][k0]);
#pragma unroll
            for (int cf = 0; cf < 2; ++cf){
                const int col = nb + cf * 16 + lrow;
                bf16x8 bv = *reinterpret_cast<const bf16x8*>(WV + (size_t)col * 128 + k0);
                bf16x8 bg = *reinterpret_cast<const bf16x8*>(WG + (size_t)col * 128 + k0);
#pragma unroll
                for (int rf = 0; rf < 4; ++rf){
                    accV[rf][cf] = __builtin_amdgcn_mfma_f32_16x16x32_bf16(af[rf], bv, accV[rf][cf], 0, 0, 0);
                    accG[rf][cf] = __builtin_amdgcn_mfma_f32_16x16x32_bf16(af[rf], bg, accG[rf][cf], 0, 0, 0);
                }
            }
        }
        // gate + transpose-stage [c][row] in wave-local LDS (no barrier needed)
#pragma unroll
        for (int cf = 0; cf < 2; ++cf){
            const int col = nb + cf * 16 + lrow;
            const float bVv = bV[col], bGv = bG[col];
#pragma unroll
            for (int rf = 0; rf < 4; ++rf){
                ushort4 pk;
#pragma unroll
                for (int j = 0; j < 4; ++j){
                    const float vv = accV[rf][cf][j] + bVv;
                    const float gg = accG[rf][cf][j] + bGv;
                    ((u16*)&pk)[j] = f2bf(sigmoidf_(gg) * vv);
                }
                *reinterpret_cast<ushort4*>(&lSbuf[(size_t)(w * 32 + cf * 16 + lrow) * 72 + rf * 16 + orow]) = pk;
            }
        }
        // wave-local readback + coalesced 128B-chunk global store
#pragma unroll
        for (int it = 0; it < 4; ++it){
            const int cl = it * 8 + (l >> 3);
            const int chunk = l & 7;
            const int cg = nb + cl;
            int4 vdat = *reinterpret_cast<const int4*>(&lSbuf[(size_t)(w * 32 + cl) * 72 + chunk * 8]);
            size_t base = (((size_t)cg * 64 + kb) * Ns + b0) * 8 + (size_t)chunk * 8;
            *reinterpret_cast<int4*>(dst + base) = vdat;
        }
    }

    __syncthreads();   // all waves done with lSbuf pair-staging before og aliasing

    // og group (Wog): GEMM, gate, stage [row][c] in LDS, coalesced store
    {
        const u16* WO = Wt + (size_t)4 * 16384;
        f32x4 acc[4][2];
#pragma unroll
        for (int rf = 0; rf < 4; ++rf)
#pragma unroll
            for (int cf = 0; cf < 2; ++cf) acc[rf][cf] = zero4;
#pragma unroll
        for (int ks = 0; ks < 4; ++ks){
            const int k0 = ks * 32 + lk;
            bf16x8 af[4];
#pragma unroll
            for (int rf = 0; rf < 4; ++rf)
                af[rf] = *reinterpret_cast<const bf16x8*>(&lA[rf * 16 + lrow][k0]);
#pragma unroll
            for (int cf = 0; cf < 2; ++cf){
                bf16x8 bv = *reinterpret_cast<const bf16x8*>(WO + (size_t)(nb + cf * 16 + lrow) * 128 + k0);
#pragma unroll
                for (int rf = 0; rf < 4; ++rf)
                    acc[rf][cf] = __builtin_amdgcn_mfma_f32_16x16x32_bf16(af[rf], bv, acc[rf][cf], 0, 0, 0);
            }
        }
#pragma unroll
        for (int cf = 0; cf < 2; ++cf){
            const int col = nb + cf * 16 + lrow;
            const float bOv = bog[col];
#pragma unroll
            for (int rf = 0; rf < 4; ++rf){
#pragma unroll
                for (int j = 0; j < 4; ++j){
                    const int row = rf * 16 + orow + j;
                    lSbuf[(size_t)row * 132 + col] = f2bf(sigmoidf_(acc[rf][cf][j] + bOv));
                }
            }
        }
        __syncthreads();
        // coalesced store: per a, 8 b x 128 c = 2KB contiguous
        const int bsub = t >> 5, c4 = (t & 31) * 4;
#pragma unroll
        for (int a = 0; a < 8; ++a){
            const int row = bsub * 8 + a;
            int2 v = *reinterpret_cast<const int2*>(&lSbuf[(size_t)row * 132 + c4]);
            *reinterpret_cast<int2*>(og + (((size_t)(a0 + a) * Ns) + (b0 + bsub)) * Cc + c4) = v;
        }
    }
}

// ---------------------------------------------------------------------------
// K2: om[c][i][j] = sum_k left[c][k][i] * right[c][k][j]   (per-channel GEMM)
// 1-D grid 2048, XCD-swizzled so each XCD owns 16 whole channels.
// 2-deep register double-buffer; LDS-staged output for int4 stores.
// ---------------------------------------------------------------------------
#define K2_LOAD(AF, BF, KS) do {                                                    \
    const size_t kbrow_ = (size_t)((KS) * 4 + lkb) * Ns;                            \
    _Pragma("unroll") for (int rf = 0; rf < 4; ++rf)                                \
        AF[rf] = *reinterpret_cast<const bf16x8*>(Lc + (kbrow_ + ib + rf * 16 + lrow) * 8); \
    _Pragma("unroll") for (int cf = 0; cf < 4; ++cf)                                \
        BF[cf] = *reinterpret_cast<const bf16x8*>(Rc + (kbrow_ + jb + cf * 16 + lrow) * 8); \
} while (0)

#define K2_MM(AF, BF) do {                                                          \
    _Pragma("unroll") for (int rf = 0; rf < 4; ++rf)                                \
    _Pragma("unroll") for (int cf = 0; cf < 4; ++cf)                                \
        acc[rf][cf] = __builtin_amdgcn_mfma_f32_16x16x32_bf16(AF[rf], BF[cf], acc[rf][cf], 0, 0, 0); \
} while (0)

__global__ __launch_bounds__(256) void k2(const u16* __restrict__ left,
                                          const u16* __restrict__ right,
                                          u16* __restrict__ om)
{
    __shared__ u16 sO[128][136];
    const int bid = blockIdx.x;
    const int xcd = bid & 7, idxx = bid >> 3;
    const int virt = xcd * 256 + idxx;          // each XCD: 256 consecutive virt = 16 channels
    const int c    = virt >> 4;
    const int tile = virt & 15;
    const int iy = tile >> 2, jx = tile & 3;
    const int t = threadIdx.x, w = t >> 6, l = t & 63;
    const int wr = w >> 1, wc = w & 1;
    const int ib = iy * 128 + wr * 64;
    const int jb = jx * 128 + wc * 64;
    const int lrow = l & 15, lkb = l >> 4;
    const u16* Lc = left  + (size_t)c * (Ns * Ns);
    const u16* Rc = right + (size_t)c * (Ns * Ns);
    const f32x4 zero4 = {0.f, 0.f, 0.f, 0.f};
    f32x4 acc[4][4];
#pragma unroll
    for (int rf = 0; rf < 4; ++rf)
#pragma unroll
        for (int cf = 0; cf < 4; ++cf) acc[rf][cf] = zero4;

    bf16x8 a0f[4], b0f[4], a1f[4], b1f[4];
    K2_LOAD(a0f, b0f, 0);
#pragma unroll
    for (int ks = 0; ks < 16; ks += 2){
        K2_LOAD(a1f, b1f, ks + 1);
        K2_MM(a0f, b0f);
        if (ks + 2 < 16) K2_LOAD(a0f, b0f, ks + 2);
        K2_MM(a1f, b1f);
    }

    // stage output in LDS, store int4-coalesced
    const int orow = (l >> 4) << 2;
#pragma unroll
    for (int rf = 0; rf < 4; ++rf)
#pragma unroll
        for (int j2 = 0; j2 < 4; ++j2){
            const int rloc = wr * 64 + rf * 16 + orow + j2;
#pragma unroll
            for (int cf = 0; cf < 4; ++cf)
                sO[rloc][wc * 64 + cf * 16 + lrow] = f2bf(acc[rf][cf][j2]);
        }
    __syncthreads();
    u16* obase = om + (size_t)c * Ns * Ns + (size_t)(iy * 128) * Ns + jx * 128;
#pragma unroll
    for (int s = 0; s < 8; ++s){
        const int g = s * 256 + t;
        const int row = g >> 4, co = (g & 15) * 8;
        int4 v = *reinterpret_cast<const int4*>(&sO[row][co]);
        *reinterpret_cast<int4*>(obase + (size_t)row * Ns + co) = v;
    }
}

// ---------------------------------------------------------------------------
// K3: final = sigmoid(og) * (LN_c(out_mid) @ Wo + bo), fp32 out [i][j][c]
// Block: one i, 64 j.  Shuffle-LN; fp32 output staged in LDS for float4 stores.
// ---------------------------------------------------------------------------
__global__ __launch_bounds__(256) void k3(
    const u16* __restrict__ om, const u16* __restrict__ og, const u16* __restrict__ Wt,
    const float* __restrict__ g2, const float* __restrict__ b2, const float* __restrict__ bo,
    float* __restrict__ out)
{
    __shared__ char smem[34816];       // X [64][136] u16 | O [64][136] u16 ; reused as fp32 [64][128]
    u16* X = reinterpret_cast<u16*>(smem);             // [64][136]
    u16* O = reinterpret_cast<u16*>(smem) + 8704;      // [64][136]
    __shared__ float sg2[128], sb2[128];
    const int i  = blockIdx.y;
    const int j0 = blockIdx.x * 64;
    const int t  = threadIdx.x;
    if (t < 128){ sg2[t] = g2[t]; sb2[t] = b2[t]; }
    {   // load out_mid (transpose [c][j] -> [j][c])
        const int c = t >> 1, jh = (t & 1) * 32;
        const u16* src = om + (size_t)c * Ns * Ns + (size_t)i * Ns + j0 + jh;
#pragma unroll
        for (int s = 0; s < 8; ++s){
            ushort4 v = reinterpret_cast<const ushort4*>(src)[s];
            const int jj = jh + s * 4;
            X[(jj + 0) * 136 + c] = v.x; X[(jj + 1) * 136 + c] = v.y;
            X[(jj + 2) * 136 + c] = v.z; X[(jj + 3) * 136 + c] = v.w;
        }
    }
    {   // load og tile (natural)
        const int jj = t >> 2, qq = t & 3;
        const u16* src = og + ((size_t)i * Ns + j0 + jj) * Cc + qq * 32;
#pragma unroll
        for (int s = 0; s < 4; ++s)
            *reinterpret_cast<int4*>(&O[jj * 136 + qq * 32 + s * 8]) = reinterpret_cast<const int4*>(src)[s];
    }
    __syncthreads();
    const int r = t >> 2, q = t & 3;
    {
        float s1 = 0.f, s2v = 0.f;
#pragma unroll
        for (int e = 0; e < 32; ++e){
            const float v = bf2f(X[r * 136 + q * 32 + e]);
            s1 += v; s2v += v * v;
        }
        s1  += __shfl_xor(s1, 1);  s1  += __shfl_xor(s1, 2);
        s2v += __shfl_xor(s2v, 1); s2v += __shfl_xor(s2v, 2);
        const float mm  = s1 * (1.0f / 128.0f);
        const float rsv = rsqrtf(s2v * (1.0f / 128.0f) - mm * mm + EPSV);
#pragma unroll
        for (int e = 0; e < 32; ++e){
            const int cc = q * 32 + e;
            const float v = bf2f(X[r * 136 + cc]);
            X[r * 136 + cc] = f2bf((v - mm) * rsv * sg2[cc] + sb2[cc]);
        }
    }
    __syncthreads();
    const int w = t >> 6, l = t & 63;
    const int lrow = l & 15, lk = (l >> 4) << 3, nbv = w * 32, orow = (l >> 4) << 2;
    const u16* WO = Wt + (size_t)5 * 16384;
    const f32x4 zero4 = {0.f, 0.f, 0.f, 0.f};
    f32x4 acc[4][2];
#pragma unroll
    for (int rf = 0; rf < 4; ++rf)
#pragma unroll
        for (int cf = 0; cf < 2; ++cf) acc[rf][cf] = zero4;
#pragma unroll
    for (int ks = 0; ks < 4; ++ks){
        const int k0 = ks * 32 + lk;
        bf16x8 af[4];
#pragma unroll
        for (int rf = 0; rf < 4; ++rf)
            af[rf] = *reinterpret_cast<const bf16x8*>(&X[(rf * 16 + lrow) * 136 + k0]);
#pragma unroll
        for (int cf = 0; cf < 2; ++cf){
            bf16x8 bv = *reinterpret_cast<const bf16x8*>(WO + (size_t)(nbv + cf * 16 + lrow) * 128 + k0);
#pragma unroll
            for (int rf = 0; rf < 4; ++rf)
                acc[rf][cf] = __builtin_amdgcn_mfma_f32_16x16x32_bf16(af[rf], bv, acc[rf][cf], 0, 0, 0);
        }
    }
    // gate into registers (O still live), then re-use smem for fp32 staging
    float gv[2][4][4];
#pragma unroll
    for (int cf = 0; cf < 2; ++cf){
        const int cg = nbv + cf * 16 + lrow;
        const float bov = bo[cg];
#pragma unroll
        for (int rf = 0; rf < 4; ++rf)
#pragma unroll
            for (int j = 0; j < 4; ++j){
                const int row = rf * 16 + orow + j;
                gv[cf][rf][j] = bf2f(O[row * 136 + cg]) * (acc[rf][cf][j] + bov);
            }
    }
    __syncthreads();
    float* sF = reinterpret_cast<float*>(smem);        // [64][128]
#pragma unroll
    for (int cf = 0; cf < 2; ++cf){
        const int cg = nbv + cf * 16 + lrow;
#pragma unroll
        for (int rf = 0; rf < 4; ++rf)
#pragma unroll
            for (int j = 0; j < 4; ++j){
                const int row = rf * 16 + orow + j;
                sF[row * 128 + cg] = gv[cf][rf][j];
            }
    }
    __syncthreads();
    const float4* sF4 = reinterpret_cast<const float4*>(smem);
    float* obase = out + ((size_t)i * Ns + j0) * Cc;
#pragma unroll
    for (int s = 0; s < 8; ++s){
        const int g = s * 256 + t;          // 2048 float4 = 64 rows x 32
        const int row = g >> 5, co = (g & 31) * 4;
        float4 v = sF4[g];
        *reinterpret_cast<float4*>(obase + (size_t)row * Cc + co) = v;
    }
}

// ---------------------------------------------------------------------------
extern "C" void kernel_launch(void* const* d_in, const int* in_sizes, int n_in,
                              void* d_out, int out_size, void* d_ws, size_t ws_size,
                              hipStream_t stream)
{
    const float* x    = (const float*)d_in[0];
    const float* ling = (const float*)d_in[1];
    const float* linb = (const float*)d_in[2];
    const float* loutg= (const float*)d_in[3];
    const float* loutb= (const float*)d_in[4];
    const float* Wl   = (const float*)d_in[5];
    const float* bl   = (const float*)d_in[6];
    const float* Wr   = (const float*)d_in[7];
    const float* br   = (const float*)d_in[8];
    const float* Wo   = (const float*)d_in[9];
    const float* bo   = (const float*)d_in[10];
    const float* Wlg  = (const float*)d_in[11];
    const float* blg  = (const float*)d_in[12];
    const float* Wrg  = (const float*)d_in[13];
    const float* brg  = (const float*)d_in[14];
    const float* Wog  = (const float*)d_in[15];
    const float* bog  = (const float*)d_in[16];

    char* ws = (char*)d_ws;
    u16* Wt = (u16*)ws;
    const size_t off = 256 * 1024;
    const size_t SZ  = (size_t)33554432 * 2;   // 64 MiB per bf16 tensor
    u16* left  = (u16*)(ws + off);
    u16* right = (u16*)(ws + off + SZ);
    u16* og    = (u16*)(ws + off + 2 * SZ);
    u16* om    = (u16*)(ws + off + 3 * SZ);

    hipLaunchKernelGGL(k_prep, dim3(384), dim3(256), 0, stream, Wl, Wlg, Wr, Wrg, Wog, Wo, Wt);
    hipLaunchKernelGGL(k1, dim3(4096), dim3(256), 0, stream,
                       x, ling, linb, Wt, bl, blg, br, brg, bog, left, right, og);
    hipLaunchKernelGGL(k2, dim3(2048), dim3(256), 0, stream, left, right, om);
    hipLaunchKernelGGL(k3, dim3(8, 512), dim3(256), 0, stream, om, og, Wt, loutg, loutb, bo, (float*)d_out);
}

// Round 4
// 272.823 us; speedup vs baseline: 1.1479x; 1.0170x over previous
//
#include <hip/hip_runtime.h>
#include <hip/hip_bf16.h>
#include <cstdint>
#include <cstddef>

typedef unsigned short u16;
typedef short bf16x8 __attribute__((ext_vector_type(8)));
typedef float f32x4 __attribute__((ext_vector_type(4)));

constexpr int Ns = 512;   // N
constexpr int Dd = 128;   // D
constexpr int Cc = 128;   // C
#define EPSV 1e-5f

__device__ __forceinline__ u16 f2bf(float f){
    __hip_bfloat16 h = __float2bfloat16(f);
    return *reinterpret_cast<u16*>(&h);
}
__device__ __forceinline__ float bf2f(u16 h){
    return __uint_as_float(((uint32_t)h) << 16);
}
__device__ __forceinline__ float sigmoidf_(float x){
    return 1.0f / (1.0f + __expf(-x));
}

// ---------------------------------------------------------------------------
// K0: weights -> bf16, transposed [n][k].  Order: Wl,Wlg,Wr,Wrg,Wog,Wo
// ---------------------------------------------------------------------------
__global__ void k_prep(const float* __restrict__ Wl, const float* __restrict__ Wlg,
                       const float* __restrict__ Wr, const float* __restrict__ Wrg,
                       const float* __restrict__ Wog, const float* __restrict__ Wo,
                       u16* __restrict__ Wt){
    int idx = blockIdx.x * 256 + threadIdx.x;
    if (idx >= 6 * 16384) return;
    int m = idx >> 14; int nk = idx & 16383; int n = nk >> 7; int k = nk & 127;
    const float* W = (m == 0) ? Wl : (m == 1) ? Wlg : (m == 2) ? Wr
                   : (m == 3) ? Wrg : (m == 4) ? Wog : Wo;
    Wt[idx] = f2bf(W[k * Cc + n]);
}

// ---------------------------------------------------------------------------
// K1: LN(x) then 5 GEMMs (Wl,Wlg -> left; Wr,Wrg -> right; Wog -> og)
// Block: 64 rows = 8 a x 8 b.  256 threads / 4 waves.
// A-fragments loaded ONCE into af[4][4] (16 ds_read_b128/thread total),
// reused by all 5 GEMMs.  cf-split keeps live acc at 32 regs.
// left/right: DIRECT global ushort4 stores in k-blocked layout [c][a/8][b][a%8]
// (no LDS staging readback -> no unbarriered LDS RAW anywhere).
// og: LDS staging (barrier-protected both sides) + coalesced int2 stores.
// ---------------------------------------------------------------------------
__global__ __launch_bounds__(256, 3) void k1(
    const float* __restrict__ x, const float* __restrict__ g_ln, const float* __restrict__ b_ln,
    const u16* __restrict__ Wt,
    const float* __restrict__ bl, const float* __restrict__ blg,
    const float* __restrict__ br, const float* __restrict__ brg,
    const float* __restrict__ bog,
    u16* __restrict__ left, u16* __restrict__ right, u16* __restrict__ og)
{
    __shared__ u16  lA[64][136];       // bf16 xn tile (padded)
    __shared__ u16  lS[64][132];       // og staging only
    __shared__ float gln[128], bln[128];

    const int t   = threadIdx.x;
    const int bid = blockIdx.x;
    const int a0  = (bid >> 6) << 3;
    const int b0  = (bid & 63) << 3;
    if (t < 128){ gln[t] = g_ln[t]; bln[t] = b_ln[t]; }

    const int r = t >> 2, q = t & 3;
    const int aa = a0 + (r & 7), bb = b0 + (r >> 3);
    const float4* xrow = reinterpret_cast<const float4*>(x + ((size_t)aa * Ns + bb) * Dd);
    float4 xv[8];
    float s1 = 0.f, s2 = 0.f;
#pragma unroll
    for (int i2 = 0; i2 < 8; ++i2){
        float4 v = xrow[q + 4 * i2];
        xv[i2] = v;
        s1 += v.x + v.y + v.z + v.w;
        s2 += v.x * v.x + v.y * v.y + v.z * v.z + v.w * v.w;
    }
    s1 += __shfl_xor(s1, 1); s1 += __shfl_xor(s1, 2);
    s2 += __shfl_xor(s2, 1); s2 += __shfl_xor(s2, 2);
    const float mm  = s1 * (1.0f / 128.0f);
    const float rsv = rsqrtf(s2 * (1.0f / 128.0f) - mm * mm + EPSV);
    __syncthreads();                  // gln/bln ready
    {
#pragma unroll
        for (int i2 = 0; i2 < 8; ++i2){
            const int d = (q + 4 * i2) * 4;
            ushort4 o;
            o.x = f2bf((xv[i2].x - mm) * rsv * gln[d + 0] + bln[d + 0]);
            o.y = f2bf((xv[i2].y - mm) * rsv * gln[d + 1] + bln[d + 1]);
            o.z = f2bf((xv[i2].z - mm) * rsv * gln[d + 2] + bln[d + 2]);
            o.w = f2bf((xv[i2].w - mm) * rsv * gln[d + 3] + bln[d + 3]);
            *reinterpret_cast<ushort4*>(&lA[r][d]) = o;
        }
    }
    __syncthreads();                  // lA ready for all waves

    const int w = t >> 6, l = t & 63;
    const int lrow = l & 15, lk = (l >> 4) << 3;
    const int nb = w * 32;
    const int orow = (l >> 4) << 2;
    const int kb = a0 >> 3;
    const f32x4 zero4 = {0.f, 0.f, 0.f, 0.f};

    // Load ALL A-fragments once; reused by all 5 GEMM groups.
    bf16x8 af[4][4];                   // [ks][rf] = 16 b128 reads, 64 VGPR
#pragma unroll
    for (int ks = 0; ks < 4; ++ks)
#pragma unroll
        for (int rf = 0; rf < 4; ++rf)
            af[ks][rf] = *reinterpret_cast<const bf16x8*>(&lA[rf * 16 + lrow][ks * 32 + lk]);

#pragma unroll 1
    for (int pair = 0; pair < 2; ++pair){
        const u16* WV = Wt + (size_t)(pair * 2 + 0) * 16384;
        const u16* WG = Wt + (size_t)(pair * 2 + 1) * 16384;
        const float* bV = pair ? br : bl;
        const float* bG = pair ? brg : blg;
        u16* dst = pair ? right : left;

#pragma unroll 1
        for (int cf = 0; cf < 2; ++cf){
            const int col = nb + cf * 16 + lrow;
            f32x4 accV[4], accG[4];
#pragma unroll
            for (int rf = 0; rf < 4; ++rf){ accV[rf] = zero4; accG[rf] = zero4; }
#pragma unroll
            for (int ks = 0; ks < 4; ++ks){
                const int k0 = ks * 32 + lk;
                bf16x8 bv = *reinterpret_cast<const bf16x8*>(WV + (size_t)col * 128 + k0);
                bf16x8 bg = *reinterpret_cast<const bf16x8*>(WG + (size_t)col * 128 + k0);
#pragma unroll
                for (int rf = 0; rf < 4; ++rf)
                    accV[rf] = __builtin_amdgcn_mfma_f32_16x16x32_bf16(af[ks][rf], bv, accV[rf], 0, 0, 0);
#pragma unroll
                for (int rf = 0; rf < 4; ++rf)
                    accG[rf] = __builtin_amdgcn_mfma_f32_16x16x32_bf16(af[ks][rf], bg, accG[rf], 0, 0, 0);
            }
            // gate + DIRECT global store (k-blocked layout, ushort4 = 4 a%8 slots)
            const float bVv = bV[col], bGv = bG[col];
#pragma unroll
            for (int rf = 0; rf < 4; ++rf){
                ushort4 pk;
#pragma unroll
                for (int j = 0; j < 4; ++j){
                    const float vv = accV[rf][j] + bVv;
                    const float gg = accG[rf][j] + bGv;
                    ((u16*)&pk)[j] = f2bf(sigmoidf_(gg) * vv);
                }
                // tile row r = rf*16 + orow + j  ->  b_off = rf*2 + (orow>>3), a_off = (orow&4)+j
                const size_t base = (((size_t)col * 64 + kb) * Ns + b0 + rf * 2 + (orow >> 3)) * 8 + (orow & 4);
                *reinterpret_cast<ushort4*>(dst + base) = pk;
            }
        }
    }

    // og group (Wog): GEMM (cf-split), gate, stage [row][c], coalesced store
    {
        const u16* WO = Wt + (size_t)4 * 16384;
#pragma unroll 1
        for (int cf = 0; cf < 2; ++cf){
            const int col = nb + cf * 16 + lrow;
            f32x4 acc[4];
#pragma unroll
            for (int rf = 0; rf < 4; ++rf) acc[rf] = zero4;
#pragma unroll
            for (int ks = 0; ks < 4; ++ks){
                const int k0 = ks * 32 + lk;
                bf16x8 bv = *reinterpret_cast<const bf16x8*>(WO + (size_t)col * 128 + k0);
#pragma unroll
                for (int rf = 0; rf < 4; ++rf)
                    acc[rf] = __builtin_amdgcn_mfma_f32_16x16x32_bf16(af[ks][rf], bv, acc[rf], 0, 0, 0);
            }
            const float bOv = bog[col];
#pragma unroll
            for (int rf = 0; rf < 4; ++rf){
#pragma unroll
                for (int j = 0; j < 4; ++j){
                    const int row = rf * 16 + orow + j;
                    lS[row][col] = f2bf(sigmoidf_(acc[rf][j] + bOv));
                }
            }
        }
        __syncthreads();
        // coalesced store: per a, 8 b x 128 c = 2KB contiguous
        const int bsub = t >> 5, c4 = (t & 31) * 4;
#pragma unroll
        for (int a = 0; a < 8; ++a){
            const int row = bsub * 8 + a;
            int2 v = *reinterpret_cast<const int2*>(&lS[row][c4]);
            *reinterpret_cast<int2*>(og + (((size_t)(a0 + a) * Ns) + (b0 + bsub)) * Cc + c4) = v;
        }
    }
}

// ---------------------------------------------------------------------------
// K2: om[c][i][j] = sum_k left[c][k][i] * right[c][k][j]   (per-channel GEMM)
// 1-D grid 2048, XCD-swizzled so each XCD owns 16 whole channels.
// 2-deep register double-buffer; LDS-staged output for int4 stores.
// ---------------------------------------------------------------------------
#define K2_LOAD(AF, BF, KS) do {                                                    \
    const size_t kbrow_ = (size_t)((KS) * 4 + lkb) * Ns;                            \
    _Pragma("unroll") for (int rf = 0; rf < 4; ++rf)                                \
        AF[rf] = *reinterpret_cast<const bf16x8*>(Lc + (kbrow_ + ib + rf * 16 + lrow) * 8); \
    _Pragma("unroll") for (int cf = 0; cf < 4; ++cf)                                \
        BF[cf] = *reinterpret_cast<const bf16x8*>(Rc + (kbrow_ + jb + cf * 16 + lrow) * 8); \
} while (0)

#define K2_MM(AF, BF) do {                                                          \
    _Pragma("unroll") for (int rf = 0; rf < 4; ++rf)                                \
    _Pragma("unroll") for (int cf = 0; cf < 4; ++cf)                                \
        acc[rf][cf] = __builtin_amdgcn_mfma_f32_16x16x32_bf16(AF[rf], BF[cf], acc[rf][cf], 0, 0, 0); \
} while (0)

__global__ __launch_bounds__(256) void k2(const u16* __restrict__ left,
                                          const u16* __restrict__ right,
                                          u16* __restrict__ om)
{
    __shared__ u16 sO[128][136];
    const int bid = blockIdx.x;
    const int xcd = bid & 7, idxx = bid >> 3;
    const int virt = xcd * 256 + idxx;          // each XCD: 256 consecutive virt = 16 channels
    const int c    = virt >> 4;
    const int tile = virt & 15;
    const int iy = tile >> 2, jx = tile & 3;
    const int t = threadIdx.x, w = t >> 6, l = t & 63;
    const int wr = w >> 1, wc = w & 1;
    const int ib = iy * 128 + wr * 64;
    const int jb = jx * 128 + wc * 64;
    const int lrow = l & 15, lkb = l >> 4;
    const u16* Lc = left  + (size_t)c * (Ns * Ns);
    const u16* Rc = right + (size_t)c * (Ns * Ns);
    const f32x4 zero4 = {0.f, 0.f, 0.f, 0.f};
    f32x4 acc[4][4];
#pragma unroll
    for (int rf = 0; rf < 4; ++rf)
#pragma unroll
        for (int cf = 0; cf < 4; ++cf) acc[rf][cf] = zero4;

    bf16x8 a0f[4], b0f[4], a1f[4], b1f[4];
    K2_LOAD(a0f, b0f, 0);
#pragma unroll
    for (int ks = 0; ks < 16; ks += 2){
        K2_LOAD(a1f, b1f, ks + 1);
        K2_MM(a0f, b0f);
        if (ks + 2 < 16) K2_LOAD(a0f, b0f, ks + 2);
        K2_MM(a1f, b1f);
    }

    // stage output in LDS, store int4-coalesced
    const int orow = (l >> 4) << 2;
#pragma unroll
    for (int rf = 0; rf < 4; ++rf)
#pragma unroll
        for (int j2 = 0; j2 < 4; ++j2){
            const int rloc = wr * 64 + rf * 16 + orow + j2;
#pragma unroll
            for (int cf = 0; cf < 4; ++cf)
                sO[rloc][wc * 64 + cf * 16 + lrow] = f2bf(acc[rf][cf][j2]);
        }
    __syncthreads();
    u16* obase = om + (size_t)c * Ns * Ns + (size_t)(iy * 128) * Ns + jx * 128;
#pragma unroll
    for (int s = 0; s < 8; ++s){
        const int g = s * 256 + t;
        const int row = g >> 4, co = (g & 15) * 8;
        int4 v = *reinterpret_cast<const int4*>(&sO[row][co]);
        *reinterpret_cast<int4*>(obase + (size_t)row * Ns + co) = v;
    }
}

// ---------------------------------------------------------------------------
// K3: final = sigmoid(og) * (LN_c(out_mid) @ Wo + bo), fp32 out [i][j][c]
// Block: one i, 64 j.  Shuffle-LN; fp32 output staged in LDS for float4 stores.
// ---------------------------------------------------------------------------
__global__ __launch_bounds__(256) void k3(
    const u16* __restrict__ om, const u16* __restrict__ og, const u16* __restrict__ Wt,
    const float* __restrict__ g2, const float* __restrict__ b2, const float* __restrict__ bo,
    float* __restrict__ out)
{
    __shared__ char smem[34816];       // X [64][136] u16 | O [64][136] u16 ; reused as fp32 [64][128]
    u16* X = reinterpret_cast<u16*>(smem);             // [64][136]
    u16* O = reinterpret_cast<u16*>(smem) + 8704;      // [64][136]
    __shared__ float sg2[128], sb2[128];
    const int i  = blockIdx.y;
    const int j0 = blockIdx.x * 64;
    const int t  = threadIdx.x;
    if (t < 128){ sg2[t] = g2[t]; sb2[t] = b2[t]; }
    {   // load out_mid (transpose [c][j] -> [j][c])
        const int c = t >> 1, jh = (t & 1) * 32;
        const u16* src = om + (size_t)c * Ns * Ns + (size_t)i * Ns + j0 + jh;
#pragma unroll
        for (int s = 0; s < 8; ++s){
            ushort4 v = reinterpret_cast<const ushort4*>(src)[s];
            const int jj = jh + s * 4;
            X[(jj + 0) * 136 + c] = v.x; X[(jj + 1) * 136 + c] = v.y;
            X[(jj + 2) * 136 + c] = v.z; X[(jj + 3) * 136 + c] = v.w;
        }
    }
    {   // load og tile (natural)
        const int jj = t >> 2, qq = t & 3;
        const u16* src = og + ((size_t)i * Ns + j0 + jj) * Cc + qq * 32;
#pragma unroll
        for (int s = 0; s < 4; ++s)
            *reinterpret_cast<int4*>(&O[jj * 136 + qq * 32 + s * 8]) = reinterpret_cast<const int4*>(src)[s];
    }
    __syncthreads();
    const int r = t >> 2, q = t & 3;
    {
        float s1 = 0.f, s2v = 0.f;
#pragma unroll
        for (int e = 0; e < 32; ++e){
            const float v = bf2f(X[r * 136 + q * 32 + e]);
            s1 += v; s2v += v * v;
        }
        s1  += __shfl_xor(s1, 1);  s1  += __shfl_xor(s1, 2);
        s2v += __shfl_xor(s2v, 1); s2v += __shfl_xor(s2v, 2);
        const float mm  = s1 * (1.0f / 128.0f);
        const float rsv = rsqrtf(s2v * (1.0f / 128.0f) - mm * mm + EPSV);
#pragma unroll
        for (int e = 0; e < 32; ++e){
            const int cc = q * 32 + e;
            const float v = bf2f(X[r * 136 + cc]);
            X[r * 136 + cc] = f2bf((v - mm) * rsv * sg2[cc] + sb2[cc]);
        }
    }
    __syncthreads();
    const int w = t >> 6, l = t & 63;
    const int lrow = l & 15, lk = (l >> 4) << 3, nbv = w * 32, orow = (l >> 4) << 2;
    const u16* WO = Wt + (size_t)5 * 16384;
    const f32x4 zero4 = {0.f, 0.f, 0.f, 0.f};
    f32x4 acc[4][2];
#pragma unroll
    for (int rf = 0; rf < 4; ++rf)
#pragma unroll
        for (int cf = 0; cf < 2; ++cf) acc[rf][cf] = zero4;
#pragma unroll
    for (int ks = 0; ks < 4; ++ks){
        const int k0 = ks * 32 + lk;
        bf16x8 af[4];
#pragma unroll
        for (int rf = 0; rf < 4; ++rf)
            af[rf] = *reinterpret_cast<const bf16x8*>(&X[(rf * 16 + lrow) * 136 + k0]);
#pragma unroll
        for (int cf = 0; cf < 2; ++cf){
            bf16x8 bv = *reinterpret_cast<const bf16x8*>(WO + (size_t)(nbv + cf * 16 + lrow) * 128 + k0);
#pragma unroll
            for (int rf = 0; rf < 4; ++rf)
                acc[rf][cf] = __builtin_amdgcn_mfma_f32_16x16x32_bf16(af[rf], bv, acc[rf][cf], 0, 0, 0);
        }
    }
    // gate into registers (O still live), then re-use smem for fp32 staging
    float gv[2][4][4];
#pragma unroll
    for (int cf = 0; cf < 2; ++cf){
        const int cg = nbv + cf * 16 + lrow;
        const float bov = bo[cg];
#pragma unroll
        for (int rf = 0; rf < 4; ++rf)
#pragma unroll
            for (int j = 0; j < 4; ++j){
                const int row = rf * 16 + orow + j;
                gv[cf][rf][j] = bf2f(O[row * 136 + cg]) * (acc[rf][cf][j] + bov);
            }
    }
    __syncthreads();
    float* sF = reinterpret_cast<float*>(smem);        // [64][128]
#pragma unroll
    for (int cf = 0; cf < 2; ++cf){
        const int cg = nbv + cf * 16 + lrow;
#pragma unroll
        for (int rf = 0; rf < 4; ++rf)
#pragma unroll
            for (int j = 0; j < 4; ++j){
                const int row = rf * 16 + orow + j;
                sF[row * 128 + cg] = gv[cf][rf][j];
            }
    }
    __syncthreads();
    const float4* sF4 = reinterpret_cast<const float4*>(smem);
    float* obase = out + ((size_t)i * Ns + j0) * Cc;
#pragma unroll
    for (int s = 0; s < 8; ++s){
        const int g = s * 256 + t;          // 2048 float4 = 64 rows x 32
        const int row = g >> 5, co = (g & 31) * 4;
        float4 v = sF4[g];
        *reinterpret_cast<float4*>(obase + (size_t)row * Cc + co) = v;
    }
}

// ---------------------------------------------------------------------------
extern "C" void kernel_launch(void* const* d_in, const int* in_sizes, int n_in,
                              void* d_out, int out_size, void* d_ws, size_t ws_size,
                              hipStream_t stream)
{
    const float* x    = (const float*)d_in[0];
    const float* ling = (const float*)d_in[1];
    const float* linb = (const float*)d_in[2];
    const float* loutg= (const float*)d_in[3];
    const float* loutb= (const float*)d_in[4];
    const float* Wl   = (const float*)d_in[5];
    const float* bl   = (const float*)d_in[6];
    const float* Wr   = (const float*)d_in[7];
    const float* br   = (const float*)d_in[8];
    const float* Wo   = (const float*)d_in[9];
    const float* bo   = (const float*)d_in[10];
    const float* Wlg  = (const float*)d_in[11];
    const float* blg  = (const float*)d_in[12];
    const float* Wrg  = (const float*)d_in[13];
    const float* brg  = (const float*)d_in[14];
    const float* Wog  = (const float*)d_in[15];
    const float* bog  = (const float*)d_in[16];

    char* ws = (char*)d_ws;
    u16* Wt = (u16*)ws;
    const size_t off = 256 * 1024;
    const size_t SZ  = (size_t)33554432 * 2;   // 64 MiB per bf16 tensor
    u16* left  = (u16*)(ws + off);
    u16* right = (u16*)(ws + off + SZ);
    u16* og    = (u16*)(ws + off + 2 * SZ);
    u16* om    = (u16*)(ws + off + 3 * SZ);

    hipLaunchKernelGGL(k_prep, dim3(384), dim3(256), 0, stream, Wl, Wlg, Wr, Wrg, Wog, Wo, Wt);
    hipLaunchKernelGGL(k1, dim3(4096), dim3(256), 0, stream,
                       x, ling, linb, Wt, bl, blg, br, brg, bog, left, right, og);
    hipLaunchKernelGGL(k2, dim3(2048), dim3(256), 0, stream, left, right, om);
    hipLaunchKernelGGL(k3, dim3(8, 512), dim3(256), 0, stream, om, og, Wt, loutg, loutb, bo, (float*)d_out);
}

// Round 7
// 269.972 us; speedup vs baseline: 1.1600x; 1.0106x over previous
//
#include <hip/hip_runtime.h>
#include <hip/hip_bf16.h>
#include <cstdint>
#include <cstddef>

typedef unsigned short u16;
typedef short bf16x8 __attribute__((ext_vector_type(8)));
typedef float f32x4 __attribute__((ext_vector_type(4)));

constexpr int Ns = 512;   // N
constexpr int Dd = 128;   // D
constexpr int Cc = 128;   // C
#define EPSV 1e-5f

__device__ __forceinline__ u16 f2bf(float f){
    __hip_bfloat16 h = __float2bfloat16(f);
    return *reinterpret_cast<u16*>(&h);
}
__device__ __forceinline__ float bf2f(u16 h){
    return __uint_as_float(((uint32_t)h) << 16);
}
__device__ __forceinline__ float sigmoidf_(float x){
    return 1.0f / (1.0f + __expf(-x));
}

// ---------------------------------------------------------------------------
// K0: weights -> bf16, transposed [n][k].  Order: Wl,Wlg,Wr,Wrg,Wog,Wo
// (R4-verified linear layout)
// ---------------------------------------------------------------------------
__global__ void k_prep(const float* __restrict__ Wl, const float* __restrict__ Wlg,
                       const float* __restrict__ Wr, const float* __restrict__ Wrg,
                       const float* __restrict__ Wog, const float* __restrict__ Wo,
                       u16* __restrict__ Wt){
    int idx = blockIdx.x * 256 + threadIdx.x;
    if (idx >= 6 * 16384) return;
    int m = idx >> 14; int nk = idx & 16383; int n = nk >> 7; int k = nk & 127;
    const float* W = (m == 0) ? Wl : (m == 1) ? Wlg : (m == 2) ? Wr
                   : (m == 3) ? Wrg : (m == 4) ? Wog : Wo;
    Wt[idx] = f2bf(W[k * Cc + n]);
}

// ---------------------------------------------------------------------------
// K1: LN(x) then 5 GEMMs (Wl,Wlg -> left; Wr,Wrg -> right; Wog -> og)
// Block: 64 rows = 8 a x 8 b.  256 threads / 4 waves.
// A-fragments in registers (R4-verified).  B-fragment groups register-
// double-buffered: group g+1's 8 plain global loads issue before group g's
// MFMA+epilogue (k2-proven pattern, compiler-managed waits — no asm).
// Group 0 loads issue before the LN barriers (overlap x latency).
// left/right: direct global ushort4 stores, k-blocked [c][a/8][b][a%8]
// (R4-verified formula).  og: barrier-protected LDS staging + int2 stores.
// ---------------------------------------------------------------------------
__global__ __launch_bounds__(256) void k1(
    const float* __restrict__ x, const float* __restrict__ g_ln, const float* __restrict__ b_ln,
    const u16* __restrict__ Wt,
    const float* __restrict__ bl, const float* __restrict__ blg,
    const float* __restrict__ br, const float* __restrict__ brg,
    const float* __restrict__ bog,
    u16* __restrict__ left, u16* __restrict__ right, u16* __restrict__ og)
{
    __shared__ u16  lA[64][136];       // bf16 xn tile (padded; R4-verified)
    __shared__ u16  lS[64][132];       // og staging
    __shared__ float gln[128], bln[128];

    const int t   = threadIdx.x;
    const int bid = blockIdx.x;
    const int a0  = (bid >> 6) << 3;
    const int b0  = (bid & 63) << 3;
    const int w = t >> 6, l = t & 63;
    const int lrow = l & 15, g = l >> 4;
    const int nb = w * 32;
    const int orow = g << 2;
    const int kb = a0 >> 3;

    // ---- B-group load helpers (plain per-lane loads; L2-resident weights) ----
    auto LOADP = [&](int mV, int mG, int cf, bf16x8 (&bv)[4], bf16x8 (&bg)[4]){
        const u16* WV = Wt + (size_t)mV * 16384;
        const u16* WG = Wt + (size_t)mG * 16384;
        const int col = nb + cf * 16 + lrow;
#pragma unroll
        for (int ks = 0; ks < 4; ++ks){
            bv[ks] = *reinterpret_cast<const bf16x8*>(WV + (size_t)col * 128 + ks * 32 + g * 8);
            bg[ks] = *reinterpret_cast<const bf16x8*>(WG + (size_t)col * 128 + ks * 32 + g * 8);
        }
    };
    auto LOAD1 = [&](int mV, int cf, bf16x8 (&bv)[4]){
        const u16* WV = Wt + (size_t)mV * 16384;
        const int col = nb + cf * 16 + lrow;
#pragma unroll
        for (int ks = 0; ks < 4; ++ks)
            bv[ks] = *reinterpret_cast<const bf16x8*>(WV + (size_t)col * 128 + ks * 32 + g * 8);
    };

    // ---- x loads first; then group-0 B loads (overlap prologue latency) ----
    const int r = t >> 2, q = t & 3;
    const int aa = a0 + (r & 7), bb = b0 + (r >> 3);
    const float4* xrow = reinterpret_cast<const float4*>(x + ((size_t)aa * Ns + bb) * Dd);
    float4 xv[8];
#pragma unroll
    for (int i2 = 0; i2 < 8; ++i2) xv[i2] = xrow[q + 4 * i2];

    bf16x8 bvA[4], bgA[4], bvB[4], bgB[4];
    LOADP(0, 1, 0, bvA, bgA);          // pair L, cf=0 — in flight across prologue

    if (t < 128){ gln[t] = g_ln[t]; bln[t] = b_ln[t]; }

    // ---- LN stats: 4-lane shuffle reduce ----
    float s1 = 0.f, s2 = 0.f;
#pragma unroll
    for (int i2 = 0; i2 < 8; ++i2){
        float4 v = xv[i2];
        s1 += v.x + v.y + v.z + v.w;
        s2 += v.x * v.x + v.y * v.y + v.z * v.z + v.w * v.w;
    }
    s1 += __shfl_xor(s1, 1); s1 += __shfl_xor(s1, 2);
    s2 += __shfl_xor(s2, 1); s2 += __shfl_xor(s2, 2);
    const float mm  = s1 * (1.0f / 128.0f);
    const float rsv = rsqrtf(s2 * (1.0f / 128.0f) - mm * mm + EPSV);
    __syncthreads();                   // gln/bln ready
#pragma unroll
    for (int i2 = 0; i2 < 8; ++i2){
        const int d = (q + 4 * i2) * 4;
        ushort4 o;
        o.x = f2bf((xv[i2].x - mm) * rsv * gln[d + 0] + bln[d + 0]);
        o.y = f2bf((xv[i2].y - mm) * rsv * gln[d + 1] + bln[d + 1]);
        o.z = f2bf((xv[i2].z - mm) * rsv * gln[d + 2] + bln[d + 2]);
        o.w = f2bf((xv[i2].w - mm) * rsv * gln[d + 3] + bln[d + 3]);
        *reinterpret_cast<ushort4*>(&lA[r][d]) = o;
    }
    __syncthreads();                   // lA ready (read-only afterwards)

    // ---- A-fragments once (R4-verified) ----
    bf16x8 af[4][4];
#pragma unroll
    for (int ks = 0; ks < 4; ++ks)
#pragma unroll
        for (int rf = 0; rf < 4; ++rf)
            af[ks][rf] = *reinterpret_cast<const bf16x8*>(&lA[rf * 16 + lrow][ks * 32 + g * 8]);

    const f32x4 zero4 = {0.f, 0.f, 0.f, 0.f};
    f32x4 aV[4], aG[4];
    auto Z2 = [&](){
#pragma unroll
        for (int rf = 0; rf < 4; ++rf){ aV[rf] = zero4; aG[rf] = zero4; }
    };
    auto MMVG = [&](const bf16x8 (&bv)[4], const bf16x8 (&bg)[4]){
#pragma unroll
        for (int ks = 0; ks < 4; ++ks){
#pragma unroll
            for (int rf = 0; rf < 4; ++rf)
                aV[rf] = __builtin_amdgcn_mfma_f32_16x16x32_bf16(af[ks][rf], bv[ks], aV[rf], 0, 0, 0);
#pragma unroll
            for (int rf = 0; rf < 4; ++rf)
                aG[rf] = __builtin_amdgcn_mfma_f32_16x16x32_bf16(af[ks][rf], bg[ks], aG[rf], 0, 0, 0);
        }
    };
    auto MMV = [&](const bf16x8 (&bv)[4]){
#pragma unroll
        for (int ks = 0; ks < 4; ++ks)
#pragma unroll
            for (int rf = 0; rf < 4; ++rf)
                aV[rf] = __builtin_amdgcn_mfma_f32_16x16x32_bf16(af[ks][rf], bv[ks], aV[rf], 0, 0, 0);
    };
    // gate + direct k-blocked global store for one cf group (R4-verified formula)
    auto EPI1 = [&](u16* dst, const float* bV, const float* bG, int cf){
        const int col = nb + cf * 16 + lrow;
        const float bVv = bV[col], bGv = bG[col];
#pragma unroll
        for (int rf = 0; rf < 4; ++rf){
            ushort4 pk;
#pragma unroll
            for (int j = 0; j < 4; ++j){
                const float vv = aV[rf][j] + bVv;
                const float gg = aG[rf][j] + bGv;
                ((u16*)&pk)[j] = f2bf(sigmoidf_(gg) * vv);
            }
            const size_t base = (((size_t)col * 64 + kb) * Ns + b0 + rf * 2 + (orow >> 3)) * 8 + (orow & 4);
            *reinterpret_cast<ushort4*>(dst + base) = pk;
        }
    };
    auto OG1 = [&](int cf){
        const int col = nb + cf * 16 + lrow;
        const float bOv = bog[col];
#pragma unroll
        for (int rf = 0; rf < 4; ++rf)
#pragma unroll
            for (int j = 0; j < 4; ++j){
                const int row = rf * 16 + orow + j;
                lS[row][col] = f2bf(sigmoidf_(aV[rf][j] + bOv));
            }
    };

    // ---- register-double-buffered group pipeline (6 groups) ----
    LOADP(0, 1, 1, bvB, bgB);                       // G1 in flight
    Z2(); MMVG(bvA, bgA); EPI1(left, bl, blg, 0);   // G0: L cf0
    LOADP(2, 3, 0, bvA, bgA);                       // G2 in flight
    Z2(); MMVG(bvB, bgB); EPI1(left, bl, blg, 1);   // G1: L cf1
    LOADP(2, 3, 1, bvB, bgB);                       // G3 in flight
    Z2(); MMVG(bvA, bgA); EPI1(right, br, brg, 0);  // G2: R cf0
    LOAD1(4, 0, bvA);                               // G4 (og cf0) in flight
    Z2(); MMVG(bvB, bgB); EPI1(right, br, brg, 1);  // G3: R cf1
    LOAD1(4, 1, bvB);                               // G5 (og cf1) in flight
#pragma unroll
    for (int rf = 0; rf < 4; ++rf) aV[rf] = zero4;
    MMV(bvA); OG1(0);                               // G4: og cf0
#pragma unroll
    for (int rf = 0; rf < 4; ++rf) aV[rf] = zero4;
    MMV(bvB); OG1(1);                               // G5: og cf1

    // ---- og global stores: barrier-protected staging readback ----
    __syncthreads();
    const int bsub = t >> 5, c4 = (t & 31) * 4;
#pragma unroll
    for (int a = 0; a < 8; ++a){
        const int row = bsub * 8 + a;
        int2 v = *reinterpret_cast<const int2*>(&lS[row][c4]);
        *reinterpret_cast<int2*>(og + (((size_t)(a0 + a) * Ns) + (b0 + bsub)) * Cc + c4) = v;
    }
}

// ---------------------------------------------------------------------------
// K2: om[c][i][j] = sum_k left[c][k][i] * right[c][k][j]   (per-channel GEMM)
// 1-D grid 2048, XCD-swizzled so each XCD owns 16 whole channels.
// ---------------------------------------------------------------------------
#define K2_LOAD(AF, BF, KS) do {                                                    \
    const size_t kbrow_ = (size_t)((KS) * 4 + lkb) * Ns;                            \
    _Pragma("unroll") for (int rf = 0; rf < 4; ++rf)                                \
        AF[rf] = *reinterpret_cast<const bf16x8*>(Lc + (kbrow_ + ib + rf * 16 + lrow) * 8); \
    _Pragma("unroll") for (int cf = 0; cf < 4; ++cf)                                \
        BF[cf] = *reinterpret_cast<const bf16x8*>(Rc + (kbrow_ + jb + cf * 16 + lrow) * 8); \
} while (0)

#define K2_MM(AF, BF) do {                                                          \
    _Pragma("unroll") for (int rf = 0; rf < 4; ++rf)                                \
    _Pragma("unroll") for (int cf = 0; cf < 4; ++cf)                                \
        acc[rf][cf] = __builtin_amdgcn_mfma_f32_16x16x32_bf16(AF[rf], BF[cf], acc[rf][cf], 0, 0, 0); \
} while (0)

__global__ __launch_bounds__(256) void k2(const u16* __restrict__ left,
                                          const u16* __restrict__ right,
                                          u16* __restrict__ om)
{
    __shared__ u16 sO[128][136];
    const int bid = blockIdx.x;
    const int xcd = bid & 7, idxx = bid >> 3;
    const int virt = xcd * 256 + idxx;
    const int c    = virt >> 4;
    const int tile = virt & 15;
    const int iy = tile >> 2, jx = tile & 3;
    const int t = threadIdx.x, w = t >> 6, l = t & 63;
    const int wr = w >> 1, wc = w & 1;
    const int ib = iy * 128 + wr * 64;
    const int jb = jx * 128 + wc * 64;
    const int lrow = l & 15, lkb = l >> 4;
    const u16* Lc = left  + (size_t)c * (Ns * Ns);
    const u16* Rc = right + (size_t)c * (Ns * Ns);
    const f32x4 zero4 = {0.f, 0.f, 0.f, 0.f};
    f32x4 acc[4][4];
#pragma unroll
    for (int rf = 0; rf < 4; ++rf)
#pragma unroll
        for (int cf = 0; cf < 4; ++cf) acc[rf][cf] = zero4;

    bf16x8 a0f[4], b0f[4], a1f[4], b1f[4];
    K2_LOAD(a0f, b0f, 0);
#pragma unroll
    for (int ks = 0; ks < 16; ks += 2){
        K2_LOAD(a1f, b1f, ks + 1);
        K2_MM(a0f, b0f);
        if (ks + 2 < 16) K2_LOAD(a0f, b0f, ks + 2);
        K2_MM(a1f, b1f);
    }

    const int orow = (l >> 4) << 2;
#pragma unroll
    for (int rf = 0; rf < 4; ++rf)
#pragma unroll
        for (int j2 = 0; j2 < 4; ++j2){
            const int rloc = wr * 64 + rf * 16 + orow + j2;
#pragma unroll
            for (int cf = 0; cf < 4; ++cf)
                sO[rloc][wc * 64 + cf * 16 + lrow] = f2bf(acc[rf][cf][j2]);
        }
    __syncthreads();
    u16* obase = om + (size_t)c * Ns * Ns + (size_t)(iy * 128) * Ns + jx * 128;
#pragma unroll
    for (int s = 0; s < 8; ++s){
        const int gg = s * 256 + t;
        const int row = gg >> 4, co = (gg & 15) * 8;
        int4 v = *reinterpret_cast<const int4*>(&sO[row][co]);
        *reinterpret_cast<int4*>(obase + (size_t)row * Ns + co) = v;
    }
}

// ---------------------------------------------------------------------------
// K3: final = sigmoid(og) * (LN_c(out_mid) @ Wo + bo), fp32 out [i][j][c]
// ---------------------------------------------------------------------------
__global__ __launch_bounds__(256) void k3(
    const u16* __restrict__ om, const u16* __restrict__ og, const u16* __restrict__ Wt,
    const float* __restrict__ g2, const float* __restrict__ b2, const float* __restrict__ bo,
    float* __restrict__ out)
{
    __shared__ char smem[34816];
    u16* X = reinterpret_cast<u16*>(smem);
    u16* O = reinterpret_cast<u16*>(smem) + 8704;
    __shared__ float sg2[128], sb2[128];
    const int i  = blockIdx.y;
    const int j0 = blockIdx.x * 64;
    const int t  = threadIdx.x;
    if (t < 128){ sg2[t] = g2[t]; sb2[t] = b2[t]; }
    {
        const int c = t >> 1, jh = (t & 1) * 32;
        const u16* src = om + (size_t)c * Ns * Ns + (size_t)i * Ns + j0 + jh;
#pragma unroll
        for (int s = 0; s < 8; ++s){
            ushort4 v = reinterpret_cast<const ushort4*>(src)[s];
            const int jj = jh + s * 4;
            X[(jj + 0) * 136 + c] = v.x; X[(jj + 1) * 136 + c] = v.y;
            X[(jj + 2) * 136 + c] = v.z; X[(jj + 3) * 136 + c] = v.w;
        }
    }
    {
        const int jj = t >> 2, qq = t & 3;
        const u16* src = og + ((size_t)i * Ns + j0 + jj) * Cc + qq * 32;
#pragma unroll
        for (int s = 0; s < 4; ++s)
            *reinterpret_cast<int4*>(&O[jj * 136 + qq * 32 + s * 8]) = reinterpret_cast<const int4*>(src)[s];
    }
    __syncthreads();
    const int r = t >> 2, q = t & 3;
    {
        float s1 = 0.f, s2v = 0.f;
#pragma unroll
        for (int e = 0; e < 32; ++e){
            const float v = bf2f(X[r * 136 + q * 32 + e]);
            s1 += v; s2v += v * v;
        }
        s1  += __shfl_xor(s1, 1);  s1  += __shfl_xor(s1, 2);
        s2v += __shfl_xor(s2v, 1); s2v += __shfl_xor(s2v, 2);
        const float mm  = s1 * (1.0f / 128.0f);
        const float rsv = rsqrtf(s2v * (1.0f / 128.0f) - mm * mm + EPSV);
#pragma unroll
        for (int e = 0; e < 32; ++e){
            const int cc = q * 32 + e;
            const float v = bf2f(X[r * 136 + cc]);
            X[r * 136 + cc] = f2bf((v - mm) * rsv * sg2[cc] + sb2[cc]);
        }
    }
    __syncthreads();
    const int w = t >> 6, l = t & 63;
    const int lrow = l & 15, lk = (l >> 4) << 3, nbv = w * 32, orow = (l >> 4) << 2;
    const u16* WO = Wt + (size_t)5 * 16384;
    const f32x4 zero4 = {0.f, 0.f, 0.f, 0.f};
    f32x4 acc[4][2];
#pragma unroll
    for (int rf = 0; rf < 4; ++rf)
#pragma unroll
        for (int cf = 0; cf < 2; ++cf) acc[rf][cf] = zero4;
#pragma unroll
    for (int ks = 0; ks < 4; ++ks){
        const int k0 = ks * 32 + lk;
        bf16x8 af[4];
#pragma unroll
        for (int rf = 0; rf < 4; ++rf)
            af[rf] = *reinterpret_cast<const bf16x8*>(&X[(rf * 16 + lrow) * 136 + k0]);
#pragma unroll
        for (int cf = 0; cf < 2; ++cf){
            bf16x8 bv = *reinterpret_cast<const bf16x8*>(WO + (size_t)(nbv + cf * 16 + lrow) * 128 + k0);
#pragma unroll
            for (int rf = 0; rf < 4; ++rf)
                acc[rf][cf] = __builtin_amdgcn_mfma_f32_16x16x32_bf16(af[rf], bv, acc[rf][cf], 0, 0, 0);
        }
    }
    float gv[2][4][4];
#pragma unroll
    for (int cf = 0; cf < 2; ++cf){
        const int cg = nbv + cf * 16 + lrow;
        const float bov = bo[cg];
#pragma unroll
        for (int rf = 0; rf < 4; ++rf)
#pragma unroll
            for (int j = 0; j < 4; ++j){
                const int row = rf * 16 + orow + j;
                gv[cf][rf][j] = bf2f(O[row * 136 + cg]) * (acc[rf][cf][j] + bov);
            }
    }
    __syncthreads();
    float* sF = reinterpret_cast<float*>(smem);
#pragma unroll
    for (int cf = 0; cf < 2; ++cf){
        const int cg = nbv + cf * 16 + lrow;
#pragma unroll
        for (int rf = 0; rf < 4; ++rf)
#pragma unroll
            for (int j = 0; j < 4; ++j){
                const int row = rf * 16 + orow + j;
                sF[row * 128 + cg] = gv[cf][rf][j];
            }
    }
    __syncthreads();
    const float4* sF4 = reinterpret_cast<const float4*>(smem);
    float* obase = out + ((size_t)i * Ns + j0) * Cc;
#pragma unroll
    for (int s = 0; s < 8; ++s){
        const int gg = s * 256 + t;
        const int row = gg >> 5, co = (gg & 31) * 4;
        float4 v = sF4[gg];
        *reinterpret_cast<float4*>(obase + (size_t)row * Cc + co) = v;
    }
}

// ---------------------------------------------------------------------------
extern "C" void kernel_launch(void* const* d_in, const int* in_sizes, int n_in,
                              void* d_out, int out_size, void* d_ws, size_t ws_size,
                              hipStream_t stream)
{
    const float* x    = (const float*)d_in[0];
    const float* ling = (const float*)d_in[1];
    const float* linb = (const float*)d_in[2];
    const float* loutg= (const float*)d_in[3];
    const float* loutb= (const float*)d_in[4];
    const float* Wl   = (const float*)d_in[5];
    const float* bl   = (const float*)d_in[6];
    const float* Wr   = (const float*)d_in[7];
    const float* br   = (const float*)d_in[8];
    const float* Wo   = (const float*)d_in[9];
    const float* bo   = (const float*)d_in[10];
    const float* Wlg  = (const float*)d_in[11];
    const float* blg  = (const float*)d_in[12];
    const float* Wrg  = (const float*)d_in[13];
    const float* brg  = (const float*)d_in[14];
    const float* Wog  = (const float*)d_in[15];
    const float* bog  = (const float*)d_in[16];

    char* ws = (char*)d_ws;
    u16* Wt = (u16*)ws;
    const size_t off = 256 * 1024;
    const size_t SZ  = (size_t)33554432 * 2;   // 64 MiB per bf16 tensor
    u16* left  = (u16*)(ws + off);
    u16* right = (u16*)(ws + off + SZ);
    u16* og    = (u16*)(ws + off + 2 * SZ);
    u16* om    = (u16*)(ws + off + 3 * SZ);

    hipLaunchKernelGGL(k_prep, dim3(384), dim3(256), 0, stream, Wl, Wlg, Wr, Wrg, Wog, Wo, Wt);
    hipLaunchKernelGGL(k1, dim3(4096), dim3(256), 0, stream,
                       x, ling, linb, Wt, bl, blg, br, brg, bog, left, right, og);
    hipLaunchKernelGGL(k2, dim3(2048), dim3(256), 0, stream, left, right, om);
    hipLaunchKernelGGL(k3, dim3(8, 512), dim3(256), 0, stream, om, og, Wt, loutg, loutb, bo, (float*)d_out);
}

// Round 8
// 253.786 us; speedup vs baseline: 1.2340x; 1.0638x over previous
//
#include <hip/hip_runtime.h>
#include <hip/hip_bf16.h>
#include <cstdint>
#include <cstddef>

typedef unsigned short u16;
typedef short bf16x8 __attribute__((ext_vector_type(8)));
typedef float f32x4 __attribute__((ext_vector_type(4)));

constexpr int Ns = 512;   // N
constexpr int Dd = 128;   // D
constexpr int Cc = 128;   // C
#define EPSV 1e-5f

__device__ __forceinline__ u16 f2bf(float f){
    __hip_bfloat16 h = __float2bfloat16(f);
    return *reinterpret_cast<u16*>(&h);
}
__device__ __forceinline__ float bf2f(u16 h){
    return __uint_as_float(((uint32_t)h) << 16);
}
__device__ __forceinline__ float sigmoidf_(float x){
    return __builtin_amdgcn_rcpf(1.0f + __expf(-x));   // rcp: ~1ulp, fine at bf16
}

// ---------------------------------------------------------------------------
// K0: weights -> bf16, transposed [n][k].  Order: Wl,Wlg,Wr,Wrg,Wog,Wo
// (R4-verified linear layout)
// ---------------------------------------------------------------------------
__global__ void k_prep(const float* __restrict__ Wl, const float* __restrict__ Wlg,
                       const float* __restrict__ Wr, const float* __restrict__ Wrg,
                       const float* __restrict__ Wog, const float* __restrict__ Wo,
                       u16* __restrict__ Wt){
    int idx = blockIdx.x * 256 + threadIdx.x;
    if (idx >= 6 * 16384) return;
    int m = idx >> 14; int nk = idx & 16383; int n = nk >> 7; int k = nk & 127;
    const float* W = (m == 0) ? Wl : (m == 1) ? Wlg : (m == 2) ? Wr
                   : (m == 3) ? Wrg : (m == 4) ? Wog : Wo;
    Wt[idx] = f2bf(W[k * Cc + n]);
}

// ---------------------------------------------------------------------------
// K1: LN(x) then 5 GEMMs (Wl,Wlg -> left; Wr,Wrg -> right; Wog -> og)
// Block: 64 rows = 8 a x 8 b.  256 threads / 4 waves.
// One shared buffer SB aliased across barrier-separated phases:
//   phase 1: xn tile [64][136]      (source of af registers)
//   phase 2: left stage [128][68]   (gated bf16, then coalesced int4 store)
//   phase 3: right stage [128][68]
//   phase 4: og stage [64][132]     (then coalesced int2 store)
// Per-cf accumulators (32 live) + af[4][4] (64); no B double buffer.
// Epilogue global stores are 128B-coalesced (was: 8B scattered).
// ---------------------------------------------------------------------------
__global__ __launch_bounds__(256) void k1(
    const float* __restrict__ x, const float* __restrict__ g_ln, const float* __restrict__ b_ln,
    const u16* __restrict__ Wt,
    const float* __restrict__ bl, const float* __restrict__ blg,
    const float* __restrict__ br, const float* __restrict__ brg,
    const float* __restrict__ bog,
    u16* __restrict__ left, u16* __restrict__ right, u16* __restrict__ og)
{
    __shared__ u16  SB[8704];          // 17.0 KB, aliased phases (all barrier-protected)
    __shared__ float gln[128], bln[128];

    const int t   = threadIdx.x;
    const int bid = blockIdx.x;
    const int a0  = (bid >> 6) << 3;
    const int b0  = (bid & 63) << 3;
    const int w = t >> 6, l = t & 63;
    const int lrow = l & 15, g = l >> 4;
    const int nb = w * 32;
    const int orow = g << 2;
    const int kb = a0 >> 3;

    // ---- prologue: x loads, LN stats, normalize into SB-as-lA ----
    const int r = t >> 2, q = t & 3;
    const int aa = a0 + (r & 7), bb = b0 + (r >> 3);
    const float4* xrow = reinterpret_cast<const float4*>(x + ((size_t)aa * Ns + bb) * Dd);
    float4 xv[8];
#pragma unroll
    for (int i2 = 0; i2 < 8; ++i2) xv[i2] = xrow[q + 4 * i2];
    if (t < 128){ gln[t] = g_ln[t]; bln[t] = b_ln[t]; }

    float s1 = 0.f, s2 = 0.f;
#pragma unroll
    for (int i2 = 0; i2 < 8; ++i2){
        float4 v = xv[i2];
        s1 += v.x + v.y + v.z + v.w;
        s2 += v.x * v.x + v.y * v.y + v.z * v.z + v.w * v.w;
    }
    s1 += __shfl_xor(s1, 1); s1 += __shfl_xor(s1, 2);
    s2 += __shfl_xor(s2, 1); s2 += __shfl_xor(s2, 2);
    const float mm  = s1 * (1.0f / 128.0f);
    const float rsv = rsqrtf(s2 * (1.0f / 128.0f) - mm * mm + EPSV);
    __syncthreads();                   // gln/bln ready
#pragma unroll
    for (int i2 = 0; i2 < 8; ++i2){
        const int d = (q + 4 * i2) * 4;
        ushort4 o;
        o.x = f2bf((xv[i2].x - mm) * rsv * gln[d + 0] + bln[d + 0]);
        o.y = f2bf((xv[i2].y - mm) * rsv * gln[d + 1] + bln[d + 1]);
        o.z = f2bf((xv[i2].z - mm) * rsv * gln[d + 2] + bln[d + 2]);
        o.w = f2bf((xv[i2].w - mm) * rsv * gln[d + 3] + bln[d + 3]);
        *reinterpret_cast<ushort4*>(&SB[r * 136 + d]) = o;
    }
    __syncthreads();                   // xn ready

    // ---- A-fragments once (R4-verified) ----
    bf16x8 af[4][4];
#pragma unroll
    for (int ks = 0; ks < 4; ++ks)
#pragma unroll
        for (int rf = 0; rf < 4; ++rf)
            af[ks][rf] = *reinterpret_cast<const bf16x8*>(&SB[(rf * 16 + lrow) * 136 + ks * 32 + g * 8]);
    __syncthreads();                   // all af reads done; SB free for staging

    const f32x4 zero4 = {0.f, 0.f, 0.f, 0.f};
    f32x4 aV[4], aG[4];

    // GEMM one cf group of a V/G pair (acc live: 32 regs)
    auto GEMM1 = [&](const u16* WV, const u16* WG, int cf){
        const int col = nb + cf * 16 + lrow;
#pragma unroll
        for (int rf = 0; rf < 4; ++rf){ aV[rf] = zero4; aG[rf] = zero4; }
#pragma unroll
        for (int ks = 0; ks < 4; ++ks){
            bf16x8 bv = *reinterpret_cast<const bf16x8*>(WV + (size_t)col * 128 + ks * 32 + g * 8);
            bf16x8 bg = *reinterpret_cast<const bf16x8*>(WG + (size_t)col * 128 + ks * 32 + g * 8);
#pragma unroll
            for (int rf = 0; rf < 4; ++rf)
                aV[rf] = __builtin_amdgcn_mfma_f32_16x16x32_bf16(af[ks][rf], bv, aV[rf], 0, 0, 0);
#pragma unroll
            for (int rf = 0; rf < 4; ++rf)
                aG[rf] = __builtin_amdgcn_mfma_f32_16x16x32_bf16(af[ks][rf], bg, aG[rf], 0, 0, 0);
        }
    };
    // gate + stage into SB[col][r_tile] (stride 68; r_tile = rf*16+orow+j)
    auto STW = [&](const float* bV, const float* bG, int cf){
        const int col = nb + cf * 16 + lrow;
        const float bVv = bV[col], bGv = bG[col];
#pragma unroll
        for (int rf = 0; rf < 4; ++rf){
            ushort4 pk;
#pragma unroll
            for (int j = 0; j < 4; ++j){
                const float vv = aV[rf][j] + bVv;
                const float gg = aG[rf][j] + bGv;
                ((u16*)&pk)[j] = f2bf(sigmoidf_(gg) * vv);
            }
            *reinterpret_cast<ushort4*>(&SB[col * 68 + rf * 16 + orow]) = pk;
        }
    };
    // coalesced store: per c, 64 contiguous u16 (=128B); 8 threads cover one c
    auto STORE = [&](u16* dst){
#pragma unroll
        for (int it = 0; it < 4; ++it){
            const int cl = it * 32 + (t >> 3);
            const int s  = t & 7;
            int4 v = *reinterpret_cast<const int4*>(&SB[cl * 68 + s * 8]);
            *reinterpret_cast<int4*>(dst + (((size_t)cl * 64 + kb) * Ns + b0) * 8 + s * 8) = v;
        }
    };

    // ---- L pair ----
    GEMM1(Wt,             Wt + 16384,     0); STW(bl, blg, 0);
    GEMM1(Wt,             Wt + 16384,     1); STW(bl, blg, 1);
    __syncthreads();
    STORE(left);
    __syncthreads();
    // ---- R pair ----
    GEMM1(Wt + 2 * 16384, Wt + 3 * 16384, 0); STW(br, brg, 0);
    GEMM1(Wt + 2 * 16384, Wt + 3 * 16384, 1); STW(br, brg, 1);
    __syncthreads();
    STORE(right);
    __syncthreads();

    // ---- og: GEMM (V only), stage [64][132], coalesced int2 store (R7-verified) ----
    const u16* WO = Wt + (size_t)4 * 16384;
#pragma unroll 1
    for (int cf = 0; cf < 2; ++cf){
        const int col = nb + cf * 16 + lrow;
#pragma unroll
        for (int rf = 0; rf < 4; ++rf) aV[rf] = zero4;
#pragma unroll
        for (int ks = 0; ks < 4; ++ks){
            bf16x8 bv = *reinterpret_cast<const bf16x8*>(WO + (size_t)col * 128 + ks * 32 + g * 8);
#pragma unroll
            for (int rf = 0; rf < 4; ++rf)
                aV[rf] = __builtin_amdgcn_mfma_f32_16x16x32_bf16(af[ks][rf], bv, aV[rf], 0, 0, 0);
        }
        const float bOv = bog[col];
#pragma unroll
        for (int rf = 0; rf < 4; ++rf)
#pragma unroll
            for (int j = 0; j < 4; ++j){
                const int row = rf * 16 + orow + j;
                SB[row * 132 + col] = f2bf(sigmoidf_(aV[rf][j] + bOv));
            }
    }
    __syncthreads();
    const int bsub = t >> 5, c4 = (t & 31) * 4;
#pragma unroll
    for (int a = 0; a < 8; ++a){
        const int row = bsub * 8 + a;
        int2 v = *reinterpret_cast<const int2*>(&SB[row * 132 + c4]);
        *reinterpret_cast<int2*>(og + (((size_t)(a0 + a) * Ns) + (b0 + bsub)) * Cc + c4) = v;
    }
}

// ---------------------------------------------------------------------------
// K2: om[c][i][j] = sum_k left[c][k][i] * right[c][k][j]   (per-channel GEMM)
// 1-D grid 2048, XCD-swizzled so each XCD owns 16 whole channels.
// ---------------------------------------------------------------------------
#define K2_LOAD(AF, BF, KS) do {                                                    \
    const size_t kbrow_ = (size_t)((KS) * 4 + lkb) * Ns;                            \
    _Pragma("unroll") for (int rf = 0; rf < 4; ++rf)                                \
        AF[rf] = *reinterpret_cast<const bf16x8*>(Lc + (kbrow_ + ib + rf * 16 + lrow) * 8); \
    _Pragma("unroll") for (int cf = 0; cf < 4; ++cf)                                \
        BF[cf] = *reinterpret_cast<const bf16x8*>(Rc + (kbrow_ + jb + cf * 16 + lrow) * 8); \
} while (0)

#define K2_MM(AF, BF) do {                                                          \
    _Pragma("unroll") for (int rf = 0; rf < 4; ++rf)                                \
    _Pragma("unroll") for (int cf = 0; cf < 4; ++cf)                                \
        acc[rf][cf] = __builtin_amdgcn_mfma_f32_16x16x32_bf16(AF[rf], BF[cf], acc[rf][cf], 0, 0, 0); \
} while (0)

__global__ __launch_bounds__(256) void k2(const u16* __restrict__ left,
                                          const u16* __restrict__ right,
                                          u16* __restrict__ om)
{
    __shared__ u16 sO[128][136];
    const int bid = blockIdx.x;
    const int xcd = bid & 7, idxx = bid >> 3;
    const int virt = xcd * 256 + idxx;
    const int c    = virt >> 4;
    const int tile = virt & 15;
    const int iy = tile >> 2, jx = tile & 3;
    const int t = threadIdx.x, w = t >> 6, l = t & 63;
    const int wr = w >> 1, wc = w & 1;
    const int ib = iy * 128 + wr * 64;
    const int jb = jx * 128 + wc * 64;
    const int lrow = l & 15, lkb = l >> 4;
    const u16* Lc = left  + (size_t)c * (Ns * Ns);
    const u16* Rc = right + (size_t)c * (Ns * Ns);
    const f32x4 zero4 = {0.f, 0.f, 0.f, 0.f};
    f32x4 acc[4][4];
#pragma unroll
    for (int rf = 0; rf < 4; ++rf)
#pragma unroll
        for (int cf = 0; cf < 4; ++cf) acc[rf][cf] = zero4;

    bf16x8 a0f[4], b0f[4], a1f[4], b1f[4];
    K2_LOAD(a0f, b0f, 0);
#pragma unroll
    for (int ks = 0; ks < 16; ks += 2){
        K2_LOAD(a1f, b1f, ks + 1);
        K2_MM(a0f, b0f);
        if (ks + 2 < 16) K2_LOAD(a0f, b0f, ks + 2);
        K2_MM(a1f, b1f);
    }

    const int orow = (l >> 4) << 2;
#pragma unroll
    for (int rf = 0; rf < 4; ++rf)
#pragma unroll
        for (int j2 = 0; j2 < 4; ++j2){
            const int rloc = wr * 64 + rf * 16 + orow + j2;
#pragma unroll
            for (int cf = 0; cf < 4; ++cf)
                sO[rloc][wc * 64 + cf * 16 + lrow] = f2bf(acc[rf][cf][j2]);
        }
    __syncthreads();
    u16* obase = om + (size_t)c * Ns * Ns + (size_t)(iy * 128) * Ns + jx * 128;
#pragma unroll
    for (int s = 0; s < 8; ++s){
        const int gg = s * 256 + t;
        const int row = gg >> 4, co = (gg & 15) * 8;
        int4 v = *reinterpret_cast<const int4*>(&sO[row][co]);
        *reinterpret_cast<int4*>(obase + (size_t)row * Ns + co) = v;
    }
}

// ---------------------------------------------------------------------------
// K3: final = sigmoid(og) * (LN_c(out_mid) @ Wo + bo), fp32 out [i][j][c]
// ---------------------------------------------------------------------------
__global__ __launch_bounds__(256) void k3(
    const u16* __restrict__ om, const u16* __restrict__ og, const u16* __restrict__ Wt,
    const float* __restrict__ g2, const float* __restrict__ b2, const float* __restrict__ bo,
    float* __restrict__ out)
{
    __shared__ char smem[34816];
    u16* X = reinterpret_cast<u16*>(smem);
    u16* O = reinterpret_cast<u16*>(smem) + 8704;
    __shared__ float sg2[128], sb2[128];
    const int i  = blockIdx.y;
    const int j0 = blockIdx.x * 64;
    const int t  = threadIdx.x;
    if (t < 128){ sg2[t] = g2[t]; sb2[t] = b2[t]; }
    {
        const int c = t >> 1, jh = (t & 1) * 32;
        const u16* src = om + (size_t)c * Ns * Ns + (size_t)i * Ns + j0 + jh;
#pragma unroll
        for (int s = 0; s < 8; ++s){
            ushort4 v = reinterpret_cast<const ushort4*>(src)[s];
            const int jj = jh + s * 4;
            X[(jj + 0) * 136 + c] = v.x; X[(jj + 1) * 136 + c] = v.y;
            X[(jj + 2) * 136 + c] = v.z; X[(jj + 3) * 136 + c] = v.w;
        }
    }
    {
        const int jj = t >> 2, qq = t & 3;
        const u16* src = og + ((size_t)i * Ns + j0 + jj) * Cc + qq * 32;
#pragma unroll
        for (int s = 0; s < 4; ++s)
            *reinterpret_cast<int4*>(&O[jj * 136 + qq * 32 + s * 8]) = reinterpret_cast<const int4*>(src)[s];
    }
    __syncthreads();
    const int r = t >> 2, q = t & 3;
    {
        float s1 = 0.f, s2v = 0.f;
#pragma unroll
        for (int e = 0; e < 32; ++e){
            const float v = bf2f(X[r * 136 + q * 32 + e]);
            s1 += v; s2v += v * v;
        }
        s1  += __shfl_xor(s1, 1);  s1  += __shfl_xor(s1, 2);
        s2v += __shfl_xor(s2v, 1); s2v += __shfl_xor(s2v, 2);
        const float mm  = s1 * (1.0f / 128.0f);
        const float rsv = rsqrtf(s2v * (1.0f / 128.0f) - mm * mm + EPSV);
#pragma unroll
        for (int e = 0; e < 32; ++e){
            const int cc = q * 32 + e;
            const float v = bf2f(X[r * 136 + cc]);
            X[r * 136 + cc] = f2bf((v - mm) * rsv * sg2[cc] + sb2[cc]);
        }
    }
    __syncthreads();
    const int w = t >> 6, l = t & 63;
    const int lrow = l & 15, lk = (l >> 4) << 3, nbv = w * 32, orow = (l >> 4) << 2;
    const u16* WO = Wt + (size_t)5 * 16384;
    const f32x4 zero4 = {0.f, 0.f, 0.f, 0.f};
    f32x4 acc[4][2];
#pragma unroll
    for (int rf = 0; rf < 4; ++rf)
#pragma unroll
        for (int cf = 0; cf < 2; ++cf) acc[rf][cf] = zero4;
#pragma unroll
    for (int ks = 0; ks < 4; ++ks){
        const int k0 = ks * 32 + lk;
        bf16x8 af[4];
#pragma unroll
        for (int rf = 0; rf < 4; ++rf)
            af[rf] = *reinterpret_cast<const bf16x8*>(&X[(rf * 16 + lrow) * 136 + k0]);
#pragma unroll
        for (int cf = 0; cf < 2; ++cf){
            bf16x8 bv = *reinterpret_cast<const bf16x8*>(WO + (size_t)(nbv + cf * 16 + lrow) * 128 + k0);
#pragma unroll
            for (int rf = 0; rf < 4; ++rf)
                acc[rf][cf] = __builtin_amdgcn_mfma_f32_16x16x32_bf16(af[rf], bv, acc[rf][cf], 0, 0, 0);
        }
    }
    float gv[2][4][4];
#pragma unroll
    for (int cf = 0; cf < 2; ++cf){
        const int cg = nbv + cf * 16 + lrow;
        const float bov = bo[cg];
#pragma unroll
        for (int rf = 0; rf < 4; ++rf)
#pragma unroll
            for (int j = 0; j < 4; ++j){
                const int row = rf * 16 + orow + j;
                gv[cf][rf][j] = bf2f(O[row * 136 + cg]) * (acc[rf][cf][j] + bov);
            }
    }
    __syncthreads();
    float* sF = reinterpret_cast<float*>(smem);
#pragma unroll
    for (int cf = 0; cf < 2; ++cf){
        const int cg = nbv + cf * 16 + lrow;
#pragma unroll
        for (int rf = 0; rf < 4; ++rf)
#pragma unroll
            for (int j = 0; j < 4; ++j){
                const int row = rf * 16 + orow + j;
                sF[row * 128 + cg] = gv[cf][rf][j];
            }
    }
    __syncthreads();
    const float4* sF4 = reinterpret_cast<const float4*>(smem);
    float* obase = out + ((size_t)i * Ns + j0) * Cc;
#pragma unroll
    for (int s = 0; s < 8; ++s){
        const int gg = s * 256 + t;
        const int row = gg >> 5, co = (gg & 31) * 4;
        float4 v = sF4[gg];
        *reinterpret_cast<float4*>(obase + (size_t)row * Cc + co) = v;
    }
}

// ---------------------------------------------------------------------------
extern "C" void kernel_launch(void* const* d_in, const int* in_sizes, int n_in,
                              void* d_out, int out_size, void* d_ws, size_t ws_size,
                              hipStream_t stream)
{
    const float* x    = (const float*)d_in[0];
    const float* ling = (const float*)d_in[1];
    const float* linb = (const float*)d_in[2];
    const float* loutg= (const float*)d_in[3];
    const float* loutb= (const float*)d_in[4];
    const float* Wl   = (const float*)d_in[5];
    const float* bl   = (const float*)d_in[6];
    const float* Wr   = (const float*)d_in[7];
    const float* br   = (const float*)d_in[8];
    const float* Wo   = (const float*)d_in[9];
    const float* bo   = (const float*)d_in[10];
    const float* Wlg  = (const float*)d_in[11];
    const float* blg  = (const float*)d_in[12];
    const float* Wrg  = (const float*)d_in[13];
    const float* brg  = (const float*)d_in[14];
    const float* Wog  = (const float*)d_in[15];
    const float* bog  = (const float*)d_in[16];

    char* ws = (char*)d_ws;
    u16* Wt = (u16*)ws;
    const size_t off = 256 * 1024;
    const size_t SZ  = (size_t)33554432 * 2;   // 64 MiB per bf16 tensor
    u16* left  = (u16*)(ws + off);
    u16* right = (u16*)(ws + off + SZ);
    u16* og    = (u16*)(ws + off + 2 * SZ);
    u16* om    = (u16*)(ws + off + 3 * SZ);

    hipLaunchKernelGGL(k_prep, dim3(384), dim3(256), 0, stream, Wl, Wlg, Wr, Wrg, Wog, Wo, Wt);
    hipLaunchKernelGGL(k1, dim3(4096), dim3(256), 0, stream,
                       x, ling, linb, Wt, bl, blg, br, brg, bog, left, right, og);
    hipLaunchKernelGGL(k2, dim3(2048), dim3(256), 0, stream, left, right, om);
    hipLaunchKernelGGL(k3, dim3(8, 512), dim3(256), 0, stream, om, og, Wt, loutg, loutb, bo, (float*)d_out);
}